// Round 2
// baseline (5401.896 us; speedup 1.0000x reference)
//
#include <hip/hip_runtime.h>
#include <math.h>

#define LQ 21760
#define NB 2
// levels: (16,16),(32,32),(64,64),(128,128); bases 0,256,1280,5376

static __device__ __forceinline__ float wave_sum(float v) {
#pragma unroll
    for (int o = 32; o > 0; o >>= 1) v += __shfl_down(v, o, 64);
    return v;
}

__global__ __launch_bounds__(256) void zero_buf(float* __restrict__ p, int n) {
    const int i = blockIdx.x * 256 + threadIdx.x;
    if (i < n) p[i] = 0.f;
}

// ---------------- generic fp32 GEMM: C = A(MxK) @ B(KxN) (+bias)(+relu) ---
// all row-major; M,N multiples of 64; K multiple of 16. grid=(N/64, M/64, batch)
__global__ __launch_bounds__(256) void gemm_rrr(
    const float* __restrict__ A, const float* __restrict__ Bm, float* __restrict__ C,
    int K, int lda, int ldb, int ldc,
    const float* __restrict__ bias, int bias_per_row, int do_relu,
    long sA, long sB, long sC)
{
    A  += (long)blockIdx.z * sA;
    Bm += (long)blockIdx.z * sB;
    C  += (long)blockIdx.z * sC;
    const int tid = threadIdx.x;
    const long m0 = (long)blockIdx.y * 64;
    const long n0 = (long)blockIdx.x * 64;
    __shared__ __align__(16) float As[16][64];
    __shared__ __align__(16) float Bs[16][64];
    const int ar = tid >> 2, ac = (tid & 3) << 2;   // A tile: 64 rows x 16 k
    const int br = tid >> 4, bc = (tid & 15) << 2;  // B tile: 16 k x 64 cols
    const int ty = tid >> 4, tx = tid & 15;
    float acc[4][4] = {};
    for (int k0 = 0; k0 < K; k0 += 16) {
        const float4 av = *reinterpret_cast<const float4*>(&A[(m0 + ar) * (long)lda + k0 + ac]);
        const float4 bv = *reinterpret_cast<const float4*>(&Bm[(long)(k0 + br) * ldb + n0 + bc]);
        __syncthreads();
        As[ac + 0][ar] = av.x; As[ac + 1][ar] = av.y;
        As[ac + 2][ar] = av.z; As[ac + 3][ar] = av.w;
        *reinterpret_cast<float4*>(&Bs[br][bc]) = bv;
        __syncthreads();
#pragma unroll
        for (int kk = 0; kk < 16; ++kk) {
            const float4 a = *reinterpret_cast<const float4*>(&As[kk][ty << 2]);
            const float4 b = *reinterpret_cast<const float4*>(&Bs[kk][tx << 2]);
            acc[0][0] += a.x * b.x; acc[0][1] += a.x * b.y; acc[0][2] += a.x * b.z; acc[0][3] += a.x * b.w;
            acc[1][0] += a.y * b.x; acc[1][1] += a.y * b.y; acc[1][2] += a.y * b.z; acc[1][3] += a.y * b.w;
            acc[2][0] += a.z * b.x; acc[2][1] += a.z * b.y; acc[2][2] += a.z * b.z; acc[2][3] += a.z * b.w;
            acc[3][0] += a.w * b.x; acc[3][1] += a.w * b.y; acc[3][2] += a.w * b.z; acc[3][3] += a.w * b.w;
        }
    }
#pragma unroll
    for (int i = 0; i < 4; ++i) {
        const long m = m0 + (ty << 2) + i;
        float4 r = make_float4(acc[i][0], acc[i][1], acc[i][2], acc[i][3]);
        if (bias) {
            if (bias_per_row) {
                const float bb = bias[m];
                r.x += bb; r.y += bb; r.z += bb; r.w += bb;
            } else {
                const float* bp = &bias[n0 + (tx << 2)];
                r.x += bp[0]; r.y += bp[1]; r.z += bp[2]; r.w += bp[3];
            }
        }
        if (do_relu) {
            r.x = fmaxf(r.x, 0.f); r.y = fmaxf(r.y, 0.f);
            r.z = fmaxf(r.z, 0.f); r.w = fmaxf(r.w, 0.f);
        }
        *reinterpret_cast<float4*>(&C[m * (long)ldc + n0 + (tx << 2)]) = r;
    }
}

// ---------------- q = src + sine_pos + level_embed (pos computed inline) ----
__global__ __launch_bounds__(256) void make_q(const float* __restrict__ src,
                                              const float* __restrict__ lvl_emb,
                                              float* __restrict__ q, long total)
{
    const long idx = (long)blockIdx.x * 256 + threadIdx.x;
    if (idx >= total) return;
    const int d = (int)(idx & 255);
    const int i = (int)((idx >> 8) % LQ);
    int lv, sz, base;
    if (i < 256)       { lv = 0; sz = 16;  base = 0; }
    else if (i < 1280) { lv = 1; sz = 32;  base = 256; }
    else if (i < 5376) { lv = 2; sz = 64;  base = 1280; }
    else               { lv = 3; sz = 128; base = 5376; }
    const int hw = i - base;
    const int hy = hw / sz, wx = hw - hy * sz;
    const int dd = d & 127;
    const float twopi = 6.283185307179586f;
    const float e = ((d < 128) ? (float)(hy + 1) : (float)(wx + 1))
                    / ((float)sz + 1e-6f) * twopi;
    const float t = powf(10000.0f, (float)(2 * (dd >> 1)) * (1.0f / 128.0f));
    const float p = e / t;
    const float v = (dd & 1) ? cosf(p) : sinf(p);
    q[idx] = src[idx] + v + lvl_emb[lv * 256 + d];
}

// ---------------- group-norm stats (atomic partial sums) --------------------
__global__ __launch_bounds__(256) void gn_stats(const float* __restrict__ z,
                                                float* __restrict__ stats,
                                                int HW, int chunks)
{
    const int bid = blockIdx.x;
    const int chunk = bid % chunks;
    const int g = (bid / chunks) & 31;
    const int b = bid / (chunks * 32);
    const int span = HW / chunks;
    const int hw0 = chunk * span;
    float s = 0.f, sq = 0.f;
    const float* base = z + ((long)b * 256 + g * 8) * HW;
    for (int c = 0; c < 8; ++c) {
        const float* p = base + (long)c * HW + hw0;
        for (int i = threadIdx.x; i < span; i += 256) {
            const float v = p[i];
            s += v; sq += v * v;
        }
    }
    s = wave_sum(s); sq = wave_sum(sq);
    __shared__ float sh[8];
    const int wid = threadIdx.x >> 6, lane = threadIdx.x & 63;
    if (lane == 0) { sh[wid] = s; sh[4 + wid] = sq; }
    __syncthreads();
    if (threadIdx.x == 0) {
        atomicAdd(&stats[(b * 32 + g) * 2 + 0], sh[0] + sh[1] + sh[2] + sh[3]);
        atomicAdd(&stats[(b * 32 + g) * 2 + 1], sh[4] + sh[5] + sh[6] + sh[7]);
    }
}

// ---------------- group-norm apply + transpose (B,D,HW)->(B,HW,D) ----------
__global__ __launch_bounds__(256) void gn_apply(const float* __restrict__ z,
                                                float* __restrict__ src,
                                                const float* __restrict__ stats,
                                                const float* __restrict__ gg,
                                                const float* __restrict__ gb,
                                                int HW, int lvl_base)
{
    __shared__ float t[32][33];
    const int b = blockIdx.z;
    const int d0 = blockIdx.y * 32;
    const int hw0 = blockIdx.x * 32;
    const int tid = threadIdx.x;
    const int cc = tid & 31, rr = tid >> 5;
#pragma unroll
    for (int k = 0; k < 4; ++k) {
        const int dl = rr + k * 8;
        t[dl][cc] = z[((long)b * 256 + d0 + dl) * HW + hw0 + cc];
    }
    __syncthreads();
    const int d = d0 + cc;
    const int g = d >> 3;
    const float s = stats[(b * 32 + g) * 2 + 0];
    const float sq = stats[(b * 32 + g) * 2 + 1];
    const float cnt = 8.0f * (float)HW;
    const float m = s / cnt;
    const float rstd = rsqrtf(sq / cnt - m * m + 1e-5f);
    const float sc = gg[d] * rstd;
    const float sb = gb[d] - m * sc;
#pragma unroll
    for (int k = 0; k < 4; ++k) {
        const int hh = rr + k * 8;
        src[((long)b * LQ + lvl_base + hw0 + hh) * 256 + d] = t[cc][hh] * sc + sb;
    }
}

// ---------------- softmax over 16 contiguous values -------------------------
__global__ __launch_bounds__(256) void softmax16(float* __restrict__ aw, long total)
{
    const long t = (long)blockIdx.x * 256 + threadIdx.x;
    if (t >= total) return;
    float4* p = reinterpret_cast<float4*>(aw + t * 16);
    float4 v0 = p[0], v1 = p[1], v2 = p[2], v3 = p[3];
    float mx = fmaxf(fmaxf(fmaxf(v0.x, v0.y), fmaxf(v0.z, v0.w)),
               fmaxf(fmaxf(fmaxf(v1.x, v1.y), fmaxf(v1.z, v1.w)),
               fmaxf(fmaxf(fmaxf(v2.x, v2.y), fmaxf(v2.z, v2.w)),
                     fmaxf(fmaxf(v3.x, v3.y), fmaxf(v3.z, v3.w)))));
    v0.x = __expf(v0.x - mx); v0.y = __expf(v0.y - mx); v0.z = __expf(v0.z - mx); v0.w = __expf(v0.w - mx);
    v1.x = __expf(v1.x - mx); v1.y = __expf(v1.y - mx); v1.z = __expf(v1.z - mx); v1.w = __expf(v1.w - mx);
    v2.x = __expf(v2.x - mx); v2.y = __expf(v2.y - mx); v2.z = __expf(v2.z - mx); v2.w = __expf(v2.w - mx);
    v3.x = __expf(v3.x - mx); v3.y = __expf(v3.y - mx); v3.z = __expf(v3.z - mx); v3.w = __expf(v3.w - mx);
    const float s = v0.x + v0.y + v0.z + v0.w + v1.x + v1.y + v1.z + v1.w
                  + v2.x + v2.y + v2.z + v2.w + v3.x + v3.y + v3.z + v3.w;
    const float inv = 1.0f / s;
    v0.x *= inv; v0.y *= inv; v0.z *= inv; v0.w *= inv;
    v1.x *= inv; v1.y *= inv; v1.z *= inv; v1.w *= inv;
    v2.x *= inv; v2.y *= inv; v2.z *= inv; v2.w *= inv;
    v3.x *= inv; v3.y *= inv; v3.z *= inv; v3.w *= inv;
    p[0] = v0; p[1] = v1; p[2] = v2; p[3] = v3;
}

// ---------------- MS deformable attention sampling --------------------------
// one wave per (b,q,h); lane = channel within head
__global__ __launch_bounds__(256) void msda(const float* __restrict__ val,
                                            const float* __restrict__ off,
                                            const float* __restrict__ aw,
                                            float* __restrict__ out)
{
    const int gw = (blockIdx.x * 256 + threadIdx.x) >> 6;  // < NB*LQ*4
    const int lane = threadIdx.x & 63;
    const int h = gw & 3;
    const long bq = gw >> 2;
    const int q = (int)(bq % LQ);
    const int b = (int)(bq / LQ);
    int Hq, Wq, bq0;
    if (q < 256)       { Hq = 16;  Wq = 16;  bq0 = 0; }
    else if (q < 1280) { Hq = 32;  Wq = 32;  bq0 = 256; }
    else if (q < 5376) { Hq = 64;  Wq = 64;  bq0 = 1280; }
    else               { Hq = 128; Wq = 128; bq0 = 5376; }
    const int hw = q - bq0;
    const int qy = hw / Wq, qx = hw - qy * Wq;
    const float refx = ((float)qx + 0.5f) / (float)Wq;
    const float refy = ((float)qy + 0.5f) / (float)Hq;
    const float* offp = off + bq * 128 + h * 32;
    const float* awp  = aw + bq * 64 + h * 16;
    const int LH[4] = {16, 32, 64, 128};
    const int LB[4] = {0, 256, 1280, 5376};
    float acc = 0.f;
#pragma unroll
    for (int lv = 0; lv < 4; ++lv) {
        const int Hl = LH[lv], Wl = LH[lv];
        const float* vb = val + ((long)b * LQ + LB[lv]) * 256 + h * 64 + lane;
#pragma unroll
        for (int p = 0; p < 4; ++p) {
            const float ox = offp[(lv * 4 + p) * 2 + 0];
            const float oy = offp[(lv * 4 + p) * 2 + 1];
            const float w = awp[lv * 4 + p];
            const float x = refx * (float)Wl + ox - 0.5f;
            const float y = refy * (float)Hl + oy - 0.5f;
            const float xf = floorf(x), yf = floorf(y);
            const float tx = x - xf, ty = y - yf;
            const int x0 = (int)xf, y0 = (int)yf;
            const float w00 = (1.f - ty) * (1.f - tx), w01 = (1.f - ty) * tx;
            const float w10 = ty * (1.f - tx),         w11 = ty * tx;
            const bool xv0 = (x0 >= 0) & (x0 < Wl);
            const bool xv1 = (x0 + 1 >= 0) & (x0 + 1 < Wl);
            if (y0 >= 0 && y0 < Hl) {
                const long r = (long)y0 * Wl;
                if (xv0) acc += w * w00 * vb[(r + x0) * 256];
                if (xv1) acc += w * w01 * vb[(r + x0 + 1) * 256];
            }
            if (y0 + 1 >= 0 && y0 + 1 < Hl) {
                const long r = (long)(y0 + 1) * Wl;
                if (xv0) acc += w * w10 * vb[(r + x0) * 256];
                if (xv1) acc += w * w11 * vb[(r + x0 + 1) * 256];
            }
        }
    }
    out[bq * 256 + h * 64 + lane] = acc;
}

// ---------------- residual + layer-norm (in place on src) -------------------
__global__ __launch_bounds__(256) void ln_residual(float* __restrict__ src,
                                                   const float* __restrict__ att,
                                                   const float* __restrict__ g,
                                                   const float* __restrict__ b)
{
    const long row = blockIdx.x;
    const int d = threadIdx.x;
    const long idx = row * 256 + d;
    const float v = src[idx] + att[idx];
    float s = wave_sum(v), sq = wave_sum(v * v);
    __shared__ float sh[8];
    const int wid = d >> 6, lane = d & 63;
    if (lane == 0) { sh[wid] = s; sh[4 + wid] = sq; }
    __syncthreads();
    const float S = sh[0] + sh[1] + sh[2] + sh[3];
    const float SQ = sh[4] + sh[5] + sh[6] + sh[7];
    const float m = S * (1.0f / 256.0f);
    const float var = SQ * (1.0f / 256.0f) - m * m;
    const float r = rsqrtf(var + 1e-5f);
    src[idx] = (v - m) * r * g[d] + b[d];
}

extern "C" void kernel_launch(void* const* d_in, const int* in_sizes, int n_in,
                              void* d_out, int out_size, void* d_ws, size_t ws_size,
                              hipStream_t stream)
{
    const float* x[4]  = {(const float*)d_in[0],  (const float*)d_in[5],
                          (const float*)d_in[10], (const float*)d_in[15]};
    const float* pw[4] = {(const float*)d_in[1],  (const float*)d_in[6],
                          (const float*)d_in[11], (const float*)d_in[16]};
    const float* pb[4] = {(const float*)d_in[2],  (const float*)d_in[7],
                          (const float*)d_in[12], (const float*)d_in[17]};
    const float* gg[4] = {(const float*)d_in[3],  (const float*)d_in[8],
                          (const float*)d_in[13], (const float*)d_in[18]};
    const float* gb[4] = {(const float*)d_in[4],  (const float*)d_in[9],
                          (const float*)d_in[14], (const float*)d_in[19]};
    const float* lvl_emb = (const float*)d_in[20];
    const float* Woff  = (const float*)d_in[21];
    const float* boff  = (const float*)d_in[22];
    const float* Wattn = (const float*)d_in[23];
    const float* battn = (const float*)d_in[24];
    const float* Wval  = (const float*)d_in[25];
    const float* bval  = (const float*)d_in[26];
    const float* Wout  = (const float*)d_in[27];
    const float* bout  = (const float*)d_in[28];
    const float* ng    = (const float*)d_in[29];
    const float* nbb   = (const float*)d_in[30];
    const float* W1    = (const float*)d_in[31];
    const float* b1    = (const float*)d_in[32];
    const float* W2    = (const float*)d_in[33];
    const float* b2    = (const float*)d_in[34];

    // ---- workspace layout (floats). d_out doubles as the "B" scratch buffer.
    const long SRC_N = (long)NB * LQ * 256;   // 11,141,120
    const long A_N   = SRC_N;                 // 11,141,120 (z / q / msda-out / FFN-hidden qtr)
    const long OFF_N = (long)NB * LQ * 128;   //  5,570,560
    const long AW_N  = (long)NB * LQ * 64;    //  2,785,280
    const long NEED  = SRC_N + A_N + OFF_N + AW_N + 512;  // 30,638,592 floats = 122.6 MB
    if (ws_size < (size_t)NEED * sizeof(float)) return;   // graceful fail (absmax) not crash

    float* ws    = (float*)d_ws;
    float* src   = ws;
    float* Abuf  = src  + SRC_N;
    float* offb  = Abuf + A_N;
    float* awb   = offb + OFF_N;
    float* stats = awb  + AW_N;
    float* Bbuf  = (float*)d_out;             // scratch: valb then attn-proj out

    zero_buf<<<2, 256, 0, stream>>>(stats, 512);

    const int LHW[4]   = {256, 1024, 4096, 16384};
    const int LC[4]    = {2048, 1024, 512, 256};
    const int LBASE[4] = {0, 256, 1280, 5376};
    for (int lv = 0; lv < 4; ++lv) {
        const int HW = LHW[lv], C = LC[lv];
        // z[b,d,hw] = pw(256xC) @ x[b](CxHW) + pb[d]   -> Abuf
        gemm_rrr<<<dim3(HW / 64, 4, NB), 256, 0, stream>>>(
            pw[lv], x[lv], Abuf, C, C, HW, HW, pb[lv], 1, 0,
            0L, (long)C * HW, (long)256 * HW);
        const int chunks = HW > 2048 ? HW / 2048 : 1;
        gn_stats<<<NB * 32 * chunks, 256, 0, stream>>>(Abuf, stats + lv * 128, HW, chunks);
        gn_apply<<<dim3(HW / 32, 8, NB), 256, 0, stream>>>(
            Abuf, src, stats + lv * 128, gg[lv], gb[lv], HW, LBASE[lv]);
    }

    const long M = (long)NB * LQ;  // 43520 = 680*64
    for (int l = 0; l < 3; ++l) {
        // q = src + pos -> Abuf
        make_q<<<(int)(M * 256 / 256), 256, 0, stream>>>(src, lvl_emb, Abuf, M * 256);
        // offsets: (M,256) @ (256,128) -> offb
        gemm_rrr<<<dim3(2, 680, 1), 256, 0, stream>>>(
            Abuf, Woff + (long)l * 256 * 128, offb, 256, 256, 128, 128,
            boff + l * 128, 0, 0, 0, 0, 0);
        // attention logits: (M,256) @ (256,64) -> awb
        gemm_rrr<<<dim3(1, 680, 1), 256, 0, stream>>>(
            Abuf, Wattn + (long)l * 256 * 64, awb, 256, 256, 64, 64,
            battn + l * 64, 0, 0, 0, 0, 0);
        softmax16<<<680, 256, 0, stream>>>(awb, M * 4);
        // value proj: (M,256) @ (256,256) from src -> Bbuf (d_out scratch)
        gemm_rrr<<<dim3(4, 680, 1), 256, 0, stream>>>(
            src, Wval + (long)l * 65536, Bbuf, 256, 256, 256, 256,
            bval + l * 256, 0, 0, 0, 0, 0);
        // sampling: reads Bbuf/offb/awb -> Abuf (q is dead)
        msda<<<43520, 256, 0, stream>>>(Bbuf, offb, awb, Abuf);
        // output proj: Abuf @ Wout -> Bbuf (valb dead)
        gemm_rrr<<<dim3(4, 680, 1), 256, 0, stream>>>(
            Abuf, Wout + (long)l * 65536, Bbuf, 256, 256, 256, 256,
            bout + l * 256, 0, 0, 0, 0, 0);
        ln_residual<<<43520, 256, 0, stream>>>(src, Bbuf, ng + l * 256, nbb + l * 256);
        // FFN in 4 row-quarters so hidden fits Abuf; layer 2 writes d_out
        float* dst = (l == 2) ? (float*)d_out : src;
        for (int qtr = 0; qtr < 4; ++qtr) {
            const long r0 = (long)qtr * (M / 4);
            gemm_rrr<<<dim3(16, 170, 1), 256, 0, stream>>>(
                src + r0 * 256, W1 + (long)l * 256 * 1024, Abuf, 256, 256, 1024, 1024,
                b1 + l * 1024, 0, 1, 0, 0, 0);
            gemm_rrr<<<dim3(4, 170, 1), 256, 0, stream>>>(
                Abuf, W2 + (long)l * 1024 * 256, dst + r0 * 256, 1024, 1024, 256, 256,
                b2 + l * 256, 0, 0, 0, 0, 0);
        }
    }
}

// Round 3
// 1909.636 us; speedup vs baseline: 2.8288x; 2.8288x over previous
//
#include <hip/hip_runtime.h>
#include <math.h>

#define LQ 21760
#define NB 2
// levels: (16,16),(32,32),(64,64),(128,128); bases 0,256,1280,5376

typedef __attribute__((ext_vector_type(8))) short bf16x8;
typedef __attribute__((ext_vector_type(4))) float f32x4;

static __device__ __forceinline__ float wave_sum(float v) {
#pragma unroll
    for (int o = 32; o > 0; o >>= 1) v += __shfl_down(v, o, 64);
    return v;
}

static __device__ __forceinline__ unsigned short f2bf(float f) {
    unsigned int u = __float_as_uint(f);
    u = (u + 0x7fffu + ((u >> 16) & 1u)) >> 16;
    return (unsigned short)u;
}
static __device__ __forceinline__ float bf2f(unsigned short h) {
    return __uint_as_float((unsigned int)h << 16);
}

__global__ __launch_bounds__(256) void zero_buf(float* __restrict__ p, int n) {
    const int i = blockIdx.x * 256 + threadIdx.x;
    if (i < n) p[i] = 0.f;
}

__global__ __launch_bounds__(256) void bias_cat(const float* __restrict__ boff,
                                                const float* __restrict__ battn,
                                                float* __restrict__ out) {
    const int idx = blockIdx.x * 256 + threadIdx.x;
    if (idx >= 3 * 192) return;
    const int l = idx / 192, i = idx - l * 192;
    out[idx] = (i < 128) ? boff[l * 128 + i] : battn[l * 64 + (i - 128)];
}

// transpose + cvt: in (Kr x Nc) fp32 -> out (Nc x Kr) bf16. grid (Nc/32, Kr/32)
__global__ __launch_bounds__(256) void transpose_cvt(const float* __restrict__ in,
                                                     unsigned short* __restrict__ out,
                                                     int Kr, int Nc)
{
    __shared__ float t[32][33];
    const int n0 = blockIdx.x * 32, k0 = blockIdx.y * 32;
    const int c = threadIdx.x & 31, r8 = threadIdx.x >> 5;
#pragma unroll
    for (int j = 0; j < 4; ++j) {
        const int r = r8 + j * 8;
        t[r][c] = in[(long)(k0 + r) * Nc + n0 + c];
    }
    __syncthreads();
#pragma unroll
    for (int j = 0; j < 4; ++j) {
        const int r = r8 + j * 8;
        out[(long)(n0 + r) * Kr + k0 + c] = f2bf(t[c][r]);
    }
}

// ---------------- generic fp32 GEMM (kept for 1x1 conv): C = A@B (+bias) ---
__global__ __launch_bounds__(256) void gemm_rrr(
    const float* __restrict__ A, const float* __restrict__ Bm, float* __restrict__ C,
    int K, int lda, int ldb, int ldc,
    const float* __restrict__ bias, int bias_per_row, int do_relu,
    long sA, long sB, long sC)
{
    A  += (long)blockIdx.z * sA;
    Bm += (long)blockIdx.z * sB;
    C  += (long)blockIdx.z * sC;
    const int tid = threadIdx.x;
    const long m0 = (long)blockIdx.y * 64;
    const long n0 = (long)blockIdx.x * 64;
    __shared__ __align__(16) float As[16][64];
    __shared__ __align__(16) float Bs[16][64];
    const int ar = tid >> 2, ac = (tid & 3) << 2;
    const int br = tid >> 4, bc = (tid & 15) << 2;
    const int ty = tid >> 4, tx = tid & 15;
    float acc[4][4] = {};
    for (int k0 = 0; k0 < K; k0 += 16) {
        const float4 av = *reinterpret_cast<const float4*>(&A[(m0 + ar) * (long)lda + k0 + ac]);
        const float4 bv = *reinterpret_cast<const float4*>(&Bm[(long)(k0 + br) * ldb + n0 + bc]);
        __syncthreads();
        As[ac + 0][ar] = av.x; As[ac + 1][ar] = av.y;
        As[ac + 2][ar] = av.z; As[ac + 3][ar] = av.w;
        *reinterpret_cast<float4*>(&Bs[br][bc]) = bv;
        __syncthreads();
#pragma unroll
        for (int kk = 0; kk < 16; ++kk) {
            const float4 a = *reinterpret_cast<const float4*>(&As[kk][ty << 2]);
            const float4 b = *reinterpret_cast<const float4*>(&Bs[kk][tx << 2]);
            acc[0][0] += a.x * b.x; acc[0][1] += a.x * b.y; acc[0][2] += a.x * b.z; acc[0][3] += a.x * b.w;
            acc[1][0] += a.y * b.x; acc[1][1] += a.y * b.y; acc[1][2] += a.y * b.z; acc[1][3] += a.y * b.w;
            acc[2][0] += a.z * b.x; acc[2][1] += a.z * b.y; acc[2][2] += a.z * b.z; acc[2][3] += a.z * b.w;
            acc[3][0] += a.w * b.x; acc[3][1] += a.w * b.y; acc[3][2] += a.w * b.z; acc[3][3] += a.w * b.w;
        }
    }
#pragma unroll
    for (int i = 0; i < 4; ++i) {
        const long m = m0 + (ty << 2) + i;
        float4 r = make_float4(acc[i][0], acc[i][1], acc[i][2], acc[i][3]);
        if (bias) {
            if (bias_per_row) {
                const float bb = bias[m];
                r.x += bb; r.y += bb; r.z += bb; r.w += bb;
            } else {
                const float* bp = &bias[n0 + (tx << 2)];
                r.x += bp[0]; r.y += bp[1]; r.z += bp[2]; r.w += bp[3];
            }
        }
        if (do_relu) {
            r.x = fmaxf(r.x, 0.f); r.y = fmaxf(r.y, 0.f);
            r.z = fmaxf(r.z, 0.f); r.w = fmaxf(r.w, 0.f);
        }
        *reinterpret_cast<float4*>(&C[m * (long)ldc + n0 + (tx << 2)]) = r;
    }
}

// ---------------- bf16 MFMA GEMM: C(MxN) = A(MxK) @ Bt(NxK)^T ---------------
// A row-major bf16 (lda=K), Bt row-major bf16 (N x K). BM=128, BK=64.
// Outputs: Cf (fp32) and/or Cb (bf16), ldc columns, bias fp32 per-col, relu.
template<int BN>
__global__ __launch_bounds__(256) void gemm_bf(
    const unsigned short* __restrict__ A, const unsigned short* __restrict__ Bt, int K,
    float* __restrict__ Cf, unsigned short* __restrict__ Cb, int ldc,
    const float* __restrict__ bias, int relu)
{
    constexpr int BM = 128, BK = 64, LDT = 72;  // LDT pad: bank-conflict-free b128
    __shared__ unsigned short As[BM * LDT];
    __shared__ unsigned short Bs[BN * LDT];
    const int tid = threadIdx.x;
    const long m0 = (long)blockIdx.y * BM;
    const int n0 = blockIdx.x * BN;
    const int wave = tid >> 6, lane = tid & 63;
    constexpr int WM = (BN == 128) ? 2 : 4;      // waves along M
    constexpr int FM = (BN == 128) ? 4 : 2;      // 16-row frags per wave
    const int wm = wave % WM, wn = wave / WM;
    const int wm0 = wm * (BM / WM), wn0 = wn * 64;
    const int lrow = lane & 15, lk8 = (lane >> 4) * 8;
    f32x4 acc[FM][4] = {};
    for (int k0 = 0; k0 < K; k0 += BK) {
        __syncthreads();
        {   // stage A: 128 rows x 64 bf16
            const int r = tid >> 1, hh = (tid & 1) * 32;
            const unsigned short* ga = A + (m0 + r) * (long)K + k0 + hh;
            uint4 v0 = *(const uint4*)(ga);
            uint4 v1 = *(const uint4*)(ga + 8);
            uint4 v2 = *(const uint4*)(ga + 16);
            uint4 v3 = *(const uint4*)(ga + 24);
            unsigned short* la = &As[r * LDT + hh];
            *(uint4*)(la) = v0; *(uint4*)(la + 8) = v1;
            *(uint4*)(la + 16) = v2; *(uint4*)(la + 24) = v3;
        }
        if constexpr (BN == 128) {
            const int r = tid >> 1, hh = (tid & 1) * 32;
            const unsigned short* gb = Bt + (n0 + r) * (long)K + k0 + hh;
            uint4 v0 = *(const uint4*)(gb);
            uint4 v1 = *(const uint4*)(gb + 8);
            uint4 v2 = *(const uint4*)(gb + 16);
            uint4 v3 = *(const uint4*)(gb + 24);
            unsigned short* lb = &Bs[r * LDT + hh];
            *(uint4*)(lb) = v0; *(uint4*)(lb + 8) = v1;
            *(uint4*)(lb + 16) = v2; *(uint4*)(lb + 24) = v3;
        } else {
            const int r = tid >> 2, q8 = (tid & 3) * 16;
            const unsigned short* gb = Bt + (n0 + r) * (long)K + k0 + q8;
            uint4 v0 = *(const uint4*)(gb);
            uint4 v1 = *(const uint4*)(gb + 8);
            unsigned short* lb = &Bs[r * LDT + q8];
            *(uint4*)(lb) = v0; *(uint4*)(lb + 8) = v1;
        }
        __syncthreads();
        bf16x8 af[FM][2], bfr[4][2];
#pragma unroll
        for (int i = 0; i < FM; ++i)
#pragma unroll
            for (int kk = 0; kk < 2; ++kk)
                af[i][kk] = *(const bf16x8*)&As[(wm0 + i * 16 + lrow) * LDT + kk * 32 + lk8];
#pragma unroll
        for (int j = 0; j < 4; ++j)
#pragma unroll
            for (int kk = 0; kk < 2; ++kk)
                bfr[j][kk] = *(const bf16x8*)&Bs[(wn0 + j * 16 + lrow) * LDT + kk * 32 + lk8];
#pragma unroll
        for (int i = 0; i < FM; ++i)
#pragma unroll
            for (int j = 0; j < 4; ++j)
#pragma unroll
                for (int kk = 0; kk < 2; ++kk)
                    acc[i][j] = __builtin_amdgcn_mfma_f32_16x16x32_bf16(
                        af[i][kk], bfr[j][kk], acc[i][j], 0, 0, 0);
    }
    const int rbase = (lane >> 4) * 4;
#pragma unroll
    for (int i = 0; i < FM; ++i) {
#pragma unroll
        for (int j = 0; j < 4; ++j) {
            const int col = n0 + wn0 + j * 16 + lrow;
            const float bb = bias ? bias[col] : 0.f;
#pragma unroll
            for (int r = 0; r < 4; ++r) {
                float v = acc[i][j][r] + bb;
                if (relu) v = fmaxf(v, 0.f);
                const long row = m0 + wm0 + i * 16 + rbase + r;
                const long idx = row * (long)ldc + col;
                if (Cf) Cf[idx] = v;
                if (Cb) Cb[idx] = f2bf(v);
            }
        }
    }
}

// ---------------- q = src + sine_pos + level_embed -> bf16 ------------------
__global__ __launch_bounds__(256) void make_q(const float* __restrict__ src,
                                              const float* __restrict__ lvl_emb,
                                              unsigned short* __restrict__ q, long total)
{
    const long idx = (long)blockIdx.x * 256 + threadIdx.x;
    if (idx >= total) return;
    const int d = (int)(idx & 255);
    const int i = (int)((idx >> 8) % LQ);
    int lv, sz;
    if (i < 256)       { lv = 0; sz = 16; }
    else if (i < 1280) { lv = 1; sz = 32; }
    else if (i < 5376) { lv = 2; sz = 64; }
    else               { lv = 3; sz = 128; }
    const int base = (lv == 0) ? 0 : (lv == 1) ? 256 : (lv == 2) ? 1280 : 5376;
    const int hw = i - base;
    const int hy = hw / sz, wx = hw - hy * sz;
    const int dd = d & 127;
    const float twopi = 6.283185307179586f;
    const float e = ((d < 128) ? (float)(hy + 1) : (float)(wx + 1))
                    / ((float)sz + 1e-6f) * twopi;
    const float t = powf(10000.0f, (float)(2 * (dd >> 1)) * (1.0f / 128.0f));
    const float p = e / t;
    const float v = (dd & 1) ? cosf(p) : sinf(p);
    q[idx] = f2bf(src[idx] + v + lvl_emb[lv * 256 + d]);
}

// ---------------- group-norm stats ------------------------------------------
__global__ __launch_bounds__(256) void gn_stats(const float* __restrict__ z,
                                                float* __restrict__ stats,
                                                int HW, int chunks)
{
    const int bid = blockIdx.x;
    const int chunk = bid % chunks;
    const int g = (bid / chunks) & 31;
    const int b = bid / (chunks * 32);
    const int span = HW / chunks;
    const int hw0 = chunk * span;
    float s = 0.f, sq = 0.f;
    const float* base = z + ((long)b * 256 + g * 8) * HW;
    for (int c = 0; c < 8; ++c) {
        const float* p = base + (long)c * HW + hw0;
        for (int i = threadIdx.x; i < span; i += 256) {
            const float v = p[i];
            s += v; sq += v * v;
        }
    }
    s = wave_sum(s); sq = wave_sum(sq);
    __shared__ float sh[8];
    const int wid = threadIdx.x >> 6, lane = threadIdx.x & 63;
    if (lane == 0) { sh[wid] = s; sh[4 + wid] = sq; }
    __syncthreads();
    if (threadIdx.x == 0) {
        atomicAdd(&stats[(b * 32 + g) * 2 + 0], sh[0] + sh[1] + sh[2] + sh[3]);
        atomicAdd(&stats[(b * 32 + g) * 2 + 1], sh[4] + sh[5] + sh[6] + sh[7]);
    }
}

// ---------------- group-norm apply + transpose, dual fp32+bf16 out ----------
__global__ __launch_bounds__(256) void gn_apply(const float* __restrict__ z,
                                                float* __restrict__ src,
                                                unsigned short* __restrict__ src_bf,
                                                const float* __restrict__ stats,
                                                const float* __restrict__ gg,
                                                const float* __restrict__ gb,
                                                int HW, int lvl_base)
{
    __shared__ float t[32][33];
    const int b = blockIdx.z;
    const int d0 = blockIdx.y * 32;
    const int hw0 = blockIdx.x * 32;
    const int tid = threadIdx.x;
    const int cc = tid & 31, rr = tid >> 5;
#pragma unroll
    for (int k = 0; k < 4; ++k) {
        const int dl = rr + k * 8;
        t[dl][cc] = z[((long)b * 256 + d0 + dl) * HW + hw0 + cc];
    }
    __syncthreads();
    const int d = d0 + cc;
    const int g = d >> 3;
    const float s = stats[(b * 32 + g) * 2 + 0];
    const float sq = stats[(b * 32 + g) * 2 + 1];
    const float cnt = 8.0f * (float)HW;
    const float m = s / cnt;
    const float rstd = rsqrtf(sq / cnt - m * m + 1e-5f);
    const float sc = gg[d] * rstd;
    const float sb = gb[d] - m * sc;
#pragma unroll
    for (int k = 0; k < 4; ++k) {
        const int hh = rr + k * 8;
        const long idx = ((long)b * LQ + lvl_base + hw0 + hh) * 256 + d;
        const float v = t[cc][hh] * sc + sb;
        src[idx] = v;
        src_bf[idx] = f2bf(v);
    }
}

// ---------------- softmax over 16 bf16 at oa[row*192 + 128 + part*16] -------
__global__ __launch_bounds__(256) void softmax16_bf(unsigned short* __restrict__ oa, long total)
{
    const long t = (long)blockIdx.x * 256 + threadIdx.x;
    if (t >= total) return;
    unsigned short* p = oa + (t >> 2) * 192 + 128 + (t & 3) * 16;
    float v[16];
    float mx = -1e30f;
#pragma unroll
    for (int i = 0; i < 16; ++i) { v[i] = bf2f(p[i]); mx = fmaxf(mx, v[i]); }
    float s = 0.f;
#pragma unroll
    for (int i = 0; i < 16; ++i) { v[i] = __expf(v[i] - mx); s += v[i]; }
    const float inv = 1.0f / s;
#pragma unroll
    for (int i = 0; i < 16; ++i) p[i] = f2bf(v[i] * inv);
}

// ---------------- MS deformable attention: wave per (b,q), float4 channels --
__global__ __launch_bounds__(256) void msda4(const float* __restrict__ val,
                                             const unsigned short* __restrict__ oa,
                                             unsigned short* __restrict__ out)
{
    const int bq = (blockIdx.x * 256 + threadIdx.x) >> 6;  // < NB*LQ
    const int lane = threadIdx.x & 63;
    const int h = lane >> 4, c4 = (lane & 15) * 4;
    const int q = bq % LQ;
    const int b = bq / LQ;
    int Hq, bq0;
    if (q < 256)       { Hq = 16;  bq0 = 0; }
    else if (q < 1280) { Hq = 32;  bq0 = 256; }
    else if (q < 5376) { Hq = 64;  bq0 = 1280; }
    else               { Hq = 128; bq0 = 5376; }
    const int hw = q - bq0;
    const int qy = hw / Hq, qx = hw - qy * Hq;
    const float refx = ((float)qx + 0.5f) / (float)Hq;
    const float refy = ((float)qy + 0.5f) / (float)Hq;
    const unsigned short* oar = oa + (long)bq * 192;
    const int LH[4] = {16, 32, 64, 128};
    const int LB[4] = {0, 256, 1280, 5376};
    float ax = 0.f, ay = 0.f, az = 0.f, aw4 = 0.f;
#pragma unroll
    for (int lv = 0; lv < 4; ++lv) {
        const int Hl = LH[lv];
        const float* vb = val + ((long)b * LQ + LB[lv]) * 256 + h * 64 + c4;
#pragma unroll
        for (int p = 0; p < 4; ++p) {
            const unsigned int oxy = *(const unsigned int*)(oar + h * 32 + (lv * 4 + p) * 2);
            const float ox = bf2f((unsigned short)(oxy & 0xffffu));
            const float oy = bf2f((unsigned short)(oxy >> 16));
            const float w = bf2f(oar[128 + h * 16 + lv * 4 + p]);
            const float x = refx * (float)Hl + ox - 0.5f;
            const float y = refy * (float)Hl + oy - 0.5f;
            const float xf = floorf(x), yf = floorf(y);
            const float tx = x - xf, ty = y - yf;
            const int x0 = (int)xf, y0 = (int)yf;
            const float w00 = w * (1.f - ty) * (1.f - tx), w01 = w * (1.f - ty) * tx;
            const float w10 = w * ty * (1.f - tx),         w11 = w * ty * tx;
            const bool xv0 = (x0 >= 0) & (x0 < Hl);
            const bool xv1 = (x0 + 1 >= 0) & (x0 + 1 < Hl);
            if (y0 >= 0 && y0 < Hl) {
                const long r = (long)y0 * Hl;
                if (xv0) { const float4 v = *(const float4*)(vb + (r + x0) * 256);
                           ax += w00 * v.x; ay += w00 * v.y; az += w00 * v.z; aw4 += w00 * v.w; }
                if (xv1) { const float4 v = *(const float4*)(vb + (r + x0 + 1) * 256);
                           ax += w01 * v.x; ay += w01 * v.y; az += w01 * v.z; aw4 += w01 * v.w; }
            }
            if (y0 + 1 >= 0 && y0 + 1 < Hl) {
                const long r = (long)(y0 + 1) * Hl;
                if (xv0) { const float4 v = *(const float4*)(vb + (r + x0) * 256);
                           ax += w10 * v.x; ay += w10 * v.y; az += w10 * v.z; aw4 += w10 * v.w; }
                if (xv1) { const float4 v = *(const float4*)(vb + (r + x0 + 1) * 256);
                           ax += w11 * v.x; ay += w11 * v.y; az += w11 * v.z; aw4 += w11 * v.w; }
            }
        }
    }
    unsigned short o4[4] = {f2bf(ax), f2bf(ay), f2bf(az), f2bf(aw4)};
    *(ushort4*)(out + (long)bq * 256 + h * 64 + c4) = *(const ushort4*)o4;
}

// ---------------- residual + layer-norm -> bf16 out -------------------------
__global__ __launch_bounds__(256) void ln_residual(const float* __restrict__ src,
                                                   const float* __restrict__ att,
                                                   unsigned short* __restrict__ outb,
                                                   const float* __restrict__ g,
                                                   const float* __restrict__ b)
{
    const long row = blockIdx.x;
    const int d = threadIdx.x;
    const long idx = row * 256 + d;
    const float v = src[idx] + att[idx];
    float s = wave_sum(v), sq = wave_sum(v * v);
    __shared__ float sh[8];
    const int wid = d >> 6, lane = d & 63;
    if (lane == 0) { sh[wid] = s; sh[4 + wid] = sq; }
    __syncthreads();
    const float S = sh[0] + sh[1] + sh[2] + sh[3];
    const float SQ = sh[4] + sh[5] + sh[6] + sh[7];
    const float m = S * (1.0f / 256.0f);
    const float var = SQ * (1.0f / 256.0f) - m * m;
    const float r = rsqrtf(var + 1e-5f);
    outb[idx] = f2bf((v - m) * r * g[d] + b[d]);
}

extern "C" void kernel_launch(void* const* d_in, const int* in_sizes, int n_in,
                              void* d_out, int out_size, void* d_ws, size_t ws_size,
                              hipStream_t stream)
{
    const float* x[4]  = {(const float*)d_in[0],  (const float*)d_in[5],
                          (const float*)d_in[10], (const float*)d_in[15]};
    const float* pw[4] = {(const float*)d_in[1],  (const float*)d_in[6],
                          (const float*)d_in[11], (const float*)d_in[16]};
    const float* pb[4] = {(const float*)d_in[2],  (const float*)d_in[7],
                          (const float*)d_in[12], (const float*)d_in[17]};
    const float* gg[4] = {(const float*)d_in[3],  (const float*)d_in[8],
                          (const float*)d_in[13], (const float*)d_in[18]};
    const float* gb[4] = {(const float*)d_in[4],  (const float*)d_in[9],
                          (const float*)d_in[14], (const float*)d_in[19]};
    const float* lvl_emb = (const float*)d_in[20];
    const float* Woff  = (const float*)d_in[21];
    const float* boff  = (const float*)d_in[22];
    const float* Wattn = (const float*)d_in[23];
    const float* battn = (const float*)d_in[24];
    const float* Wval  = (const float*)d_in[25];
    const float* bval  = (const float*)d_in[26];
    const float* Wout  = (const float*)d_in[27];
    const float* bout  = (const float*)d_in[28];
    const float* ng    = (const float*)d_in[29];
    const float* nbb   = (const float*)d_in[30];
    const float* W1    = (const float*)d_in[31];
    const float* b1    = (const float*)d_in[32];
    const float* W2    = (const float*)d_in[33];
    const float* b2    = (const float*)d_in[34];

    // ---- workspace layout (float offsets)
    const long M = (long)NB * LQ;                 // 43520
    const long SRC_F   = 0;                       // fp32 src     11,141,120 f
    const long SRCBF_F = 11141120;                // bf16 src      5,570,560 f
    const long SHARED_F = SRCBF_F + 5570560;      // bf16 q/att/ln 5,570,560 f
    const long OA_F    = SHARED_F + 5570560;      // bf16 M*192    4,177,920 f
    const long WT_F    = OA_F + 4177920;          // bf16 weights  1,056,768 f
    const long BIAS_F  = WT_F + 1056768;          // 576 f
    const long STATS_F = BIAS_F + 576;            // 512 f
    const long NEED_F  = STATS_F + 512;           // 27,518,016 f = 110.1 MB
    if (ws_size < (size_t)NEED_F * sizeof(float)) return;

    float* ws = (float*)d_ws;
    float*          src    = ws + SRC_F;
    unsigned short* src_bf = (unsigned short*)(ws + SRCBF_F);
    unsigned short* shbf   = (unsigned short*)(ws + SHARED_F);  // q_bf / att_bf / ln_bf
    unsigned short* oab    = (unsigned short*)(ws + OA_F);
    unsigned short* wT     = (unsigned short*)(ws + WT_F);
    float*          biasoa = ws + BIAS_F;
    float*          stats  = ws + STATS_F;
    float*          zbuf   = ws + SHARED_F;       // conv scratch overlays shared+oa
    float*          Bbuf   = (float*)d_out;       // val / attn-proj scratch

    // bf16 transposed weight offsets (ushort units)
    const long OAT = 0;                 // 3 * 192*256
    const long VALT = OAT + 3 * 49152;  // 3 * 65536
    const long OUTT = VALT + 3 * 65536;
    const long W1T = OUTT + 3 * 65536;  // 3 * 1024*256
    const long W2T = W1T + 3 * 262144;  // 3 * 256*1024

    zero_buf<<<2, 256, 0, stream>>>(stats, 512);
    bias_cat<<<3, 256, 0, stream>>>(boff, battn, biasoa);
    for (int l = 0; l < 3; ++l) {
        transpose_cvt<<<dim3(4, 8),  256, 0, stream>>>(Woff + (long)l * 32768,  wT + OAT + l * 49152, 256, 128);
        transpose_cvt<<<dim3(2, 8),  256, 0, stream>>>(Wattn + (long)l * 16384, wT + OAT + l * 49152 + 128 * 256, 256, 64);
        transpose_cvt<<<dim3(8, 8),  256, 0, stream>>>(Wval + (long)l * 65536,  wT + VALT + l * 65536, 256, 256);
        transpose_cvt<<<dim3(8, 8),  256, 0, stream>>>(Wout + (long)l * 65536,  wT + OUTT + l * 65536, 256, 256);
        transpose_cvt<<<dim3(32, 8), 256, 0, stream>>>(W1 + (long)l * 262144,   wT + W1T + l * 262144, 256, 1024);
        transpose_cvt<<<dim3(8, 32), 256, 0, stream>>>(W2 + (long)l * 262144,   wT + W2T + l * 262144, 1024, 256);
    }

    const int LHW[4]   = {256, 1024, 4096, 16384};
    const int LC[4]    = {2048, 1024, 512, 256};
    const int LBASE[4] = {0, 256, 1280, 5376};
    for (int lv = 0; lv < 4; ++lv) {
        const int HW = LHW[lv], C = LC[lv];
        gemm_rrr<<<dim3(HW / 64, 4, NB), 256, 0, stream>>>(
            pw[lv], x[lv], zbuf, C, C, HW, HW, pb[lv], 1, 0,
            0L, (long)C * HW, (long)256 * HW);
        const int chunks = HW > 2048 ? HW / 2048 : 1;
        gn_stats<<<NB * 32 * chunks, 256, 0, stream>>>(zbuf, stats + lv * 128, HW, chunks);
        gn_apply<<<dim3(HW / 32, 8, NB), 256, 0, stream>>>(
            zbuf, src, src_bf, stats + lv * 128, gg[lv], gb[lv], HW, LBASE[lv]);
    }

    for (int l = 0; l < 3; ++l) {
        // q = src + pos -> shbf (bf16)
        make_q<<<(int)(M), 256, 0, stream>>>(src, lvl_emb, shbf, M * 256);
        // off+attn combined: (M,256)@(256,192) -> oab bf16
        gemm_bf<64><<<dim3(3, 340), 256, 0, stream>>>(
            shbf, wT + OAT + (long)l * 49152, 256, nullptr, oab, 192,
            biasoa + l * 192, 0);
        softmax16_bf<<<680, 256, 0, stream>>>(oab, M * 4);
        // value proj: src_bf @ Wval^T -> Bbuf fp32
        gemm_bf<128><<<dim3(2, 340), 256, 0, stream>>>(
            src_bf, wT + VALT + (long)l * 65536, 256, Bbuf, nullptr, 256,
            bval + l * 256, 0);
        // sampling -> shbf bf16 (q dead)
        msda4<<<10880, 256, 0, stream>>>(Bbuf, oab, shbf);
        // output proj: shbf @ Wout^T -> Bbuf fp32 (val dead)
        gemm_bf<128><<<dim3(2, 340), 256, 0, stream>>>(
            shbf, wT + OUTT + (long)l * 65536, 256, Bbuf, nullptr, 256,
            bout + l * 256, 0);
        // residual + LN -> shbf bf16 (att dead)
        ln_residual<<<(int)M, 256, 0, stream>>>(src, Bbuf, shbf, ng + l * 256, nbb + l * 256);
        // FFN in halves; hidden bf16 lives in d_out (l<2) or dead src (l==2)
        unsigned short* hid = (l < 2) ? (unsigned short*)d_out : (unsigned short*)src;
        for (int hf = 0; hf < 2; ++hf) {
            const long r0 = (long)hf * (M / 2);
            gemm_bf<128><<<dim3(8, 170), 256, 0, stream>>>(
                shbf + r0 * 256, wT + W1T + (long)l * 262144, 256,
                nullptr, hid, 1024, b1 + l * 1024, 1);
            float* cf = ((l < 2) ? src : (float*)d_out) + r0 * 256;
            unsigned short* cb = (l < 2) ? (src_bf + r0 * 256) : nullptr;
            gemm_bf<128><<<dim3(2, 170), 256, 0, stream>>>(
                hid, wT + W2T + (long)l * 262144, 1024,
                cf, cb, 256, b2 + l * 256, 0);
        }
    }
}

// Round 7
// 1624.023 us; speedup vs baseline: 3.3262x; 1.1759x over previous
//
#include <hip/hip_runtime.h>
#include <math.h>

#define LQ 21760
#define NB 2
// levels: (16,16),(32,32),(64,64),(128,128); bases 0,256,1280,5376

typedef __attribute__((ext_vector_type(8))) short bf16x8;
typedef __attribute__((ext_vector_type(4))) float f32x4;

static __device__ __forceinline__ float wave_sum(float v) {
#pragma unroll
    for (int o = 32; o > 0; o >>= 1) v += __shfl_down(v, o, 64);
    return v;
}

static __device__ __forceinline__ unsigned short f2bf(float f) {
    unsigned int u = __float_as_uint(f);
    u = (u + 0x7fffu + ((u >> 16) & 1u)) >> 16;
    return (unsigned short)u;
}
static __device__ __forceinline__ float bf2f(unsigned short h) {
    return __uint_as_float((unsigned int)h << 16);
}

__global__ __launch_bounds__(256) void zero_buf(float* __restrict__ p, int n) {
    const int i = blockIdx.x * 256 + threadIdx.x;
    if (i < n) p[i] = 0.f;
}

__global__ __launch_bounds__(256) void bias_cat(const float* __restrict__ boff,
                                                const float* __restrict__ battn,
                                                float* __restrict__ out) {
    const int idx = blockIdx.x * 256 + threadIdx.x;
    if (idx >= 3 * 192) return;
    const int l = idx / 192, i = idx - l * 192;
    out[idx] = (i < 128) ? boff[l * 128 + i] : battn[l * 64 + (i - 128)];
}

__global__ __launch_bounds__(256) void cvt_bf(const float* __restrict__ in,
                                              unsigned short* __restrict__ out, long n) {
    const long i = (long)blockIdx.x * 256 + threadIdx.x;
    if (i < n) out[i] = f2bf(in[i]);
}

// transpose + cvt: in (Kr x Nc) fp32 -> out (Nc x Kr) bf16. grid (Nc/32, Kr/32)
__global__ __launch_bounds__(256) void transpose_cvt(const float* __restrict__ in,
                                                     unsigned short* __restrict__ out,
                                                     int Kr, int Nc)
{
    __shared__ float t[32][33];
    const int n0 = blockIdx.x * 32, k0 = blockIdx.y * 32;
    const int c = threadIdx.x & 31, r8 = threadIdx.x >> 5;
#pragma unroll
    for (int j = 0; j < 4; ++j) {
        const int r = r8 + j * 8;
        t[r][c] = in[(long)(k0 + r) * Nc + n0 + c];
    }
    __syncthreads();
#pragma unroll
    for (int j = 0; j < 4; ++j) {
        const int r = r8 + j * 8;
        out[(long)(n0 + r) * Kr + k0 + c] = f2bf(t[c][r]);
    }
}

// batch transpose+cvt: in (B, C, HW) fp32 -> out (B, HW, C) bf16. grid (HW/32, C/32, B)
__global__ __launch_bounds__(256) void transpose_cvt_x(const float* __restrict__ in,
                                                       unsigned short* __restrict__ out,
                                                       int C, int HW)
{
    __shared__ float t[32][33];
    const int hw0 = blockIdx.x * 32, c0 = blockIdx.y * 32;
    const int b = blockIdx.z;
    in  += (long)b * C * HW;
    out += (long)b * HW * C;
    const int cc = threadIdx.x & 31, rr = threadIdx.x >> 5;
#pragma unroll
    for (int j = 0; j < 4; ++j) {
        const int r = rr + j * 8;
        t[r][cc] = in[(long)(c0 + r) * HW + hw0 + cc];
    }
    __syncthreads();
#pragma unroll
    for (int j = 0; j < 4; ++j) {
        const int r = rr + j * 8;
        out[(long)(hw0 + r) * C + c0 + cc] = f2bf(t[cc][r]);
    }
}

// ---------------- bf16 MFMA GEMM: C(MxN) = A(MxK) @ Bt(NxK)^T ---------------
// A row-major bf16 (lda=K), Bt row-major bf16 (N x K). BM=128, BK=64.
template<int BN>
__global__ __launch_bounds__(256) void gemm_bf(
    const unsigned short* __restrict__ A, const unsigned short* __restrict__ Bt, int K,
    float* __restrict__ Cf, unsigned short* __restrict__ Cb, int ldc,
    const float* __restrict__ bias, int relu)
{
    constexpr int BM = 128, BK = 64, LDT = 72;
    __shared__ unsigned short As[BM * LDT];
    __shared__ unsigned short Bs[BN * LDT];
    const int tid = threadIdx.x;
    const long m0 = (long)blockIdx.y * BM;
    const int n0 = blockIdx.x * BN;
    const int wave = tid >> 6, lane = tid & 63;
    constexpr int WM = (BN == 128) ? 2 : 4;
    constexpr int FM = (BN == 128) ? 4 : 2;
    const int wm = wave % WM, wn = wave / WM;
    const int wm0 = wm * (BM / WM), wn0 = wn * 64;
    const int lrow = lane & 15, lk8 = (lane >> 4) * 8;
    f32x4 acc[FM][4] = {};
    for (int k0 = 0; k0 < K; k0 += BK) {
        __syncthreads();
        {
            const int r = tid >> 1, hh = (tid & 1) * 32;
            const unsigned short* ga = A + (m0 + r) * (long)K + k0 + hh;
            uint4 v0 = *(const uint4*)(ga);
            uint4 v1 = *(const uint4*)(ga + 8);
            uint4 v2 = *(const uint4*)(ga + 16);
            uint4 v3 = *(const uint4*)(ga + 24);
            unsigned short* la = &As[r * LDT + hh];
            *(uint4*)(la) = v0; *(uint4*)(la + 8) = v1;
            *(uint4*)(la + 16) = v2; *(uint4*)(la + 24) = v3;
        }
        if constexpr (BN == 128) {
            const int r = tid >> 1, hh = (tid & 1) * 32;
            const unsigned short* gb = Bt + (n0 + r) * (long)K + k0 + hh;
            uint4 v0 = *(const uint4*)(gb);
            uint4 v1 = *(const uint4*)(gb + 8);
            uint4 v2 = *(const uint4*)(gb + 16);
            uint4 v3 = *(const uint4*)(gb + 24);
            unsigned short* lb = &Bs[r * LDT + hh];
            *(uint4*)(lb) = v0; *(uint4*)(lb + 8) = v1;
            *(uint4*)(lb + 16) = v2; *(uint4*)(lb + 24) = v3;
        } else {
            const int r = tid >> 2, q8 = (tid & 3) * 16;
            const unsigned short* gb = Bt + (n0 + r) * (long)K + k0 + q8;
            uint4 v0 = *(const uint4*)(gb);
            uint4 v1 = *(const uint4*)(gb + 8);
            unsigned short* lb = &Bs[r * LDT + q8];
            *(uint4*)(lb) = v0; *(uint4*)(lb + 8) = v1;
        }
        __syncthreads();
        bf16x8 af[FM][2], bfr[4][2];
#pragma unroll
        for (int i = 0; i < FM; ++i)
#pragma unroll
            for (int kk = 0; kk < 2; ++kk)
                af[i][kk] = *(const bf16x8*)&As[(wm0 + i * 16 + lrow) * LDT + kk * 32 + lk8];
#pragma unroll
        for (int j = 0; j < 4; ++j)
#pragma unroll
            for (int kk = 0; kk < 2; ++kk)
                bfr[j][kk] = *(const bf16x8*)&Bs[(wn0 + j * 16 + lrow) * LDT + kk * 32 + lk8];
#pragma unroll
        for (int i = 0; i < FM; ++i)
#pragma unroll
            for (int j = 0; j < 4; ++j)
#pragma unroll
                for (int kk = 0; kk < 2; ++kk)
                    acc[i][j] = __builtin_amdgcn_mfma_f32_16x16x32_bf16(
                        af[i][kk], bfr[j][kk], acc[i][j], 0, 0, 0);
    }
    const int rbase = (lane >> 4) * 4;
#pragma unroll
    for (int i = 0; i < FM; ++i) {
#pragma unroll
        for (int j = 0; j < 4; ++j) {
            const int col = n0 + wn0 + j * 16 + lrow;
            const float bb = bias ? bias[col] : 0.f;
#pragma unroll
            for (int r = 0; r < 4; ++r) {
                float v = acc[i][j][r] + bb;
                if (relu) v = fmaxf(v, 0.f);
                const long row = m0 + wm0 + i * 16 + rbase + r;
                const long idx = row * (long)ldc + col;
                if (Cf) Cf[idx] = v;
                if (Cb) Cb[idx] = f2bf(v);
            }
        }
    }
}

// ---------------- sine pos + level embed -> bf16 table ----------------------
__global__ __launch_bounds__(256) void pos_kernel(unsigned short* __restrict__ pos,
                                                  const float* __restrict__ lvl_emb)
{
    const int idx = blockIdx.x * 256 + threadIdx.x;  // < LQ*256
    const int d = idx & 255;
    const int i = idx >> 8;
    int lv, sz;
    if (i < 256)       { lv = 0; sz = 16; }
    else if (i < 1280) { lv = 1; sz = 32; }
    else if (i < 5376) { lv = 2; sz = 64; }
    else               { lv = 3; sz = 128; }
    const int base = (lv == 0) ? 0 : (lv == 1) ? 256 : (lv == 2) ? 1280 : 5376;
    const int hw = i - base;
    const int hy = hw / sz, wx = hw - hy * sz;
    const int dd = d & 127;
    const float twopi = 6.283185307179586f;
    const float e = ((d < 128) ? (float)(hy + 1) : (float)(wx + 1))
                    / ((float)sz + 1e-6f) * twopi;
    const float t = powf(10000.0f, (float)(2 * (dd >> 1)) * (1.0f / 128.0f));
    const float p = e / t;
    const float v = (dd & 1) ? cosf(p) : sinf(p);
    pos[idx] = f2bf(v + lvl_emb[lv * 256 + d]);
}

// ---------------- q = src + pos (vectorized x4) -> bf16 ---------------------
__global__ __launch_bounds__(256) void make_q2(const float* __restrict__ src,
                                               const unsigned short* __restrict__ pos,
                                               unsigned short* __restrict__ q, long total4)
{
    const long t = (long)blockIdx.x * 256 + threadIdx.x;
    if (t >= total4) return;
    const long idx = t * 4;
    const long pe = (idx >= (long)LQ * 256) ? idx - (long)LQ * 256 : idx;
    const float4 s = *(const float4*)(src + idx);
    const ushort4 pp = *(const ushort4*)(pos + pe);
    unsigned short o[4] = {f2bf(s.x + bf2f(pp.x)), f2bf(s.y + bf2f(pp.y)),
                           f2bf(s.z + bf2f(pp.z)), f2bf(s.w + bf2f(pp.w))};
    *(ushort4*)(q + idx) = *(const ushort4*)o;
}

// ---------------- group-norm stats on (B,HW,256) layout ---------------------
// grid (HW/span, B); thread = channel d; 8-lane group reduce + atomics
__global__ __launch_bounds__(256) void gn_stats2(const float* __restrict__ z,
                                                 float* __restrict__ stats,
                                                 int HW, int span)
{
    const int b = blockIdx.y;
    const int hw0 = blockIdx.x * span;
    const int d = threadIdx.x;
    float s = 0.f, sq = 0.f;
    const float* p = z + ((long)b * HW + hw0) * 256 + d;
    for (int i = 0; i < span; ++i) {
        const float v = p[(long)i * 256];
        s += v; sq += v * v;
    }
#pragma unroll
    for (int o = 1; o < 8; o <<= 1) {
        s += __shfl_xor(s, o, 64);
        sq += __shfl_xor(sq, o, 64);
    }
    if ((d & 7) == 0) {
        atomicAdd(&stats[(b * 32 + (d >> 3)) * 2 + 0], s);
        atomicAdd(&stats[(b * 32 + (d >> 3)) * 2 + 1], sq);
    }
}

// ---------------- group-norm scale (B,HW,256) -> src fp32 + bf16 ------------
__global__ __launch_bounds__(256) void gn_scale(const float* __restrict__ z,
                                                float* __restrict__ src,
                                                unsigned short* __restrict__ src_bf,
                                                const float* __restrict__ stats,
                                                const float* __restrict__ gg,
                                                const float* __restrict__ gb,
                                                int hwShift, int lvl_base, long total4)
{
    const long t = (long)blockIdx.x * 256 + threadIdx.x;
    if (t >= total4) return;
    const int d4 = (int)(t & 63) * 4;
    const long row = t >> 6;                       // b*HW + hw
    const int b = (int)(row >> hwShift);
    const int hw = (int)(row & ((1 << hwShift) - 1));
    const int g = d4 >> 3;
    const float s = stats[(b * 32 + g) * 2 + 0];
    const float sq = stats[(b * 32 + g) * 2 + 1];
    const float cnt = 8.0f * (float)(1 << hwShift);
    const float m = s / cnt;
    const float rstd = rsqrtf(sq / cnt - m * m + 1e-5f);
    const float4 v = *(const float4*)(z + row * 256 + d4);
    float o[4];
    o[0] = (v.x - m) * rstd * gg[d4 + 0] + gb[d4 + 0];
    o[1] = (v.y - m) * rstd * gg[d4 + 1] + gb[d4 + 1];
    o[2] = (v.z - m) * rstd * gg[d4 + 2] + gb[d4 + 2];
    o[3] = (v.w - m) * rstd * gg[d4 + 3] + gb[d4 + 3];
    const long oidx = ((long)b * LQ + lvl_base + hw) * 256 + d4;
    *(float4*)(src + oidx) = make_float4(o[0], o[1], o[2], o[3]);
    unsigned short ob[4] = {f2bf(o[0]), f2bf(o[1]), f2bf(o[2]), f2bf(o[3])};
    *(ushort4*)(src_bf + oidx) = *(const ushort4*)ob;
}

// ---------------- softmax over 16 bf16 at oa[row*192 + 128 + part*16] -------
__global__ __launch_bounds__(256) void softmax16_bf(unsigned short* __restrict__ oa, long total)
{
    const long t = (long)blockIdx.x * 256 + threadIdx.x;
    if (t >= total) return;
    unsigned short* p = oa + (t >> 2) * 192 + 128 + (t & 3) * 16;
    float v[16];
    float mx = -1e30f;
#pragma unroll
    for (int i = 0; i < 16; ++i) { v[i] = bf2f(p[i]); mx = fmaxf(mx, v[i]); }
    float s = 0.f;
#pragma unroll
    for (int i = 0; i < 16; ++i) { v[i] = __expf(v[i] - mx); s += v[i]; }
    const float inv = 1.0f / s;
#pragma unroll
    for (int i = 0; i < 16; ++i) p[i] = f2bf(v[i] * inv);
}

// ---------------- MS deformable attention: wave per (b,q), bf16 values ------
__global__ __launch_bounds__(256) void msda4(const unsigned short* __restrict__ val,
                                             const unsigned short* __restrict__ oa,
                                             unsigned short* __restrict__ out)
{
    const int bq = (blockIdx.x * 256 + threadIdx.x) >> 6;  // < NB*LQ
    const int lane = threadIdx.x & 63;
    const int h = lane >> 4, c4 = (lane & 15) * 4;
    const int q = bq % LQ;
    const int b = bq / LQ;
    int Hq, bq0;
    if (q < 256)       { Hq = 16;  bq0 = 0; }
    else if (q < 1280) { Hq = 32;  bq0 = 256; }
    else if (q < 5376) { Hq = 64;  bq0 = 1280; }
    else               { Hq = 128; bq0 = 5376; }
    const int hw = q - bq0;
    const int qy = hw / Hq, qx = hw - qy * Hq;
    const float refx = ((float)qx + 0.5f) / (float)Hq;
    const float refy = ((float)qy + 0.5f) / (float)Hq;
    const unsigned short* oar = oa + (long)bq * 192;
    const int LH[4] = {16, 32, 64, 128};
    const int LB[4] = {0, 256, 1280, 5376};
    float ax = 0.f, ay = 0.f, az = 0.f, aw4 = 0.f;
#pragma unroll
    for (int lv = 0; lv < 4; ++lv) {
        const int Hl = LH[lv];
        const unsigned short* vb = val + ((long)b * LQ + LB[lv]) * 256 + h * 64 + c4;
#pragma unroll
        for (int p = 0; p < 4; ++p) {
            const unsigned int oxy = *(const unsigned int*)(oar + h * 32 + (lv * 4 + p) * 2);
            const float ox = bf2f((unsigned short)(oxy & 0xffffu));
            const float oy = bf2f((unsigned short)(oxy >> 16));
            const float w = bf2f(oar[128 + h * 16 + lv * 4 + p]);
            const float x = refx * (float)Hl + ox - 0.5f;
            const float y = refy * (float)Hl + oy - 0.5f;
            const float xf = floorf(x), yf = floorf(y);
            const float tx = x - xf, ty = y - yf;
            const int x0 = (int)xf, y0 = (int)yf;
            const float w00 = w * (1.f - ty) * (1.f - tx), w01 = w * (1.f - ty) * tx;
            const float w10 = w * ty * (1.f - tx),         w11 = w * ty * tx;
            const bool xv0 = (x0 >= 0) & (x0 < Hl);
            const bool xv1 = (x0 + 1 >= 0) & (x0 + 1 < Hl);
#define SAMPLE(WT, IDX) { const ushort4 vv = *(const ushort4*)(vb + (long)(IDX) * 256); \
        ax += (WT) * bf2f(vv.x); ay += (WT) * bf2f(vv.y); \
        az += (WT) * bf2f(vv.z); aw4 += (WT) * bf2f(vv.w); }
            if (y0 >= 0 && y0 < Hl) {
                const int r = y0 * Hl;
                if (xv0) SAMPLE(w00, r + x0)
                if (xv1) SAMPLE(w01, r + x0 + 1)
            }
            if (y0 + 1 >= 0 && y0 + 1 < Hl) {
                const int r = (y0 + 1) * Hl;
                if (xv0) SAMPLE(w10, r + x0)
                if (xv1) SAMPLE(w11, r + x0 + 1)
            }
#undef SAMPLE
        }
    }
    unsigned short o4[4] = {f2bf(ax), f2bf(ay), f2bf(az), f2bf(aw4)};
    *(ushort4*)(out + (long)bq * 256 + h * 64 + c4) = *(const ushort4*)o4;
}

// ---------------- residual + layer-norm -> bf16 out -------------------------
__global__ __launch_bounds__(256) void ln_residual(const float* __restrict__ src,
                                                   const float* __restrict__ att,
                                                   unsigned short* __restrict__ outb,
                                                   const float* __restrict__ g,
                                                   const float* __restrict__ b)
{
    const long row = blockIdx.x;
    const int d = threadIdx.x;
    const long idx = row * 256 + d;
    const float v = src[idx] + att[idx];
    float s = wave_sum(v), sq = wave_sum(v * v);
    __shared__ float sh[8];
    const int wid = d >> 6, lane = d & 63;
    if (lane == 0) { sh[wid] = s; sh[4 + wid] = sq; }
    __syncthreads();
    const float S = sh[0] + sh[1] + sh[2] + sh[3];
    const float SQ = sh[4] + sh[5] + sh[6] + sh[7];
    const float m = S * (1.0f / 256.0f);
    const float var = SQ * (1.0f / 256.0f) - m * m;
    const float r = rsqrtf(var + 1e-5f);
    outb[idx] = f2bf((v - m) * r * g[d] + b[d]);
}

extern "C" void kernel_launch(void* const* d_in, const int* in_sizes, int n_in,
                              void* d_out, int out_size, void* d_ws, size_t ws_size,
                              hipStream_t stream)
{
    const float* x[4]  = {(const float*)d_in[0],  (const float*)d_in[5],
                          (const float*)d_in[10], (const float*)d_in[15]};
    const float* pw[4] = {(const float*)d_in[1],  (const float*)d_in[6],
                          (const float*)d_in[11], (const float*)d_in[16]};
    const float* pb[4] = {(const float*)d_in[2],  (const float*)d_in[7],
                          (const float*)d_in[12], (const float*)d_in[17]};
    const float* gg[4] = {(const float*)d_in[3],  (const float*)d_in[8],
                          (const float*)d_in[13], (const float*)d_in[18]};
    const float* gb[4] = {(const float*)d_in[4],  (const float*)d_in[9],
                          (const float*)d_in[14], (const float*)d_in[19]};
    const float* lvl_emb = (const float*)d_in[20];
    const float* Woff  = (const float*)d_in[21];
    const float* boff  = (const float*)d_in[22];
    const float* Wattn = (const float*)d_in[23];
    const float* battn = (const float*)d_in[24];
    const float* Wval  = (const float*)d_in[25];
    const float* bval  = (const float*)d_in[26];
    const float* Wout  = (const float*)d_in[27];
    const float* bout  = (const float*)d_in[28];
    const float* ng    = (const float*)d_in[29];
    const float* nbb   = (const float*)d_in[30];
    const float* W1    = (const float*)d_in[31];
    const float* b1    = (const float*)d_in[32];
    const float* W2    = (const float*)d_in[33];
    const float* b2    = (const float*)d_in[34];

    // ---- workspace layout (float offsets)
    const long M = (long)NB * LQ;                 // 43520
    const long SRC_F    = 0;                      // fp32 src        11,141,120 f
    const long SRCBF_F  = 11141120;               // bf16 src         5,570,560 f
    const long SHARED_F = SRCBF_F + 5570560;      // bf16 q/att/ln    5,570,560 f
    const long OA_F     = SHARED_F + 5570560;     // bf16 M*192       4,177,920 f
    const long POS_F    = OA_F + 4177920;         // bf16 LQ*256      2,785,280 f
    const long WT_F     = POS_F + 2785280;        // bf16 weights     1,056,768 f
    const long BIAS_F   = WT_F + 1056768;         // 576 f
    const long STATS_F  = BIAS_F + 576;           // 512 f
    const long NEED_F   = STATS_F + 512;          // 30,303,296 f = 121.2 MB
    if (ws_size < (size_t)NEED_F * sizeof(float)) return;

    float* ws = (float*)d_ws;
    float*          src    = ws + SRC_F;
    unsigned short* src_bf = (unsigned short*)(ws + SRCBF_F);
    unsigned short* shbf   = (unsigned short*)(ws + SHARED_F);
    unsigned short* oab    = (unsigned short*)(ws + OA_F);
    unsigned short* posbf  = (unsigned short*)(ws + POS_F);
    unsigned short* wT     = (unsigned short*)(ws + WT_F);
    float*          biasoa = ws + BIAS_F;
    float*          stats  = ws + STATS_F;
    // conv-phase overlays: zbuf needs max 2*16384*256 = 8,388,608 f in SHARED+OA;
    // pw_bf (983,040 ushorts = 491,520 f) lives in the tail of OA after zbuf.
    float*          zbuf   = ws + SHARED_F;
    unsigned short* pwbf   = (unsigned short*)(ws + SHARED_F + 8388608);
    float*          Bbuf   = (float*)d_out;       // xT / val / attn-proj scratch

    // bf16 transposed weight offsets (ushort units)
    const long OAT = 0;                 // 3 * 192*256
    const long VALT = OAT + 3 * 49152;  // 3 * 65536
    const long OUTT = VALT + 3 * 65536;
    const long W1T = OUTT + 3 * 65536;  // 3 * 1024*256
    const long W2T = W1T + 3 * 262144;  // 3 * 256*1024

    zero_buf<<<2, 256, 0, stream>>>(stats, 512);
    bias_cat<<<3, 256, 0, stream>>>(boff, battn, biasoa);
    pos_kernel<<<LQ, 256, 0, stream>>>(posbf, lvl_emb);
    for (int l = 0; l < 3; ++l) {
        transpose_cvt<<<dim3(4, 8),  256, 0, stream>>>(Woff + (long)l * 32768,  wT + OAT + l * 49152, 256, 128);
        transpose_cvt<<<dim3(2, 8),  256, 0, stream>>>(Wattn + (long)l * 16384, wT + OAT + l * 49152 + 128 * 256, 256, 64);
        transpose_cvt<<<dim3(8, 8),  256, 0, stream>>>(Wval + (long)l * 65536,  wT + VALT + l * 65536, 256, 256);
        transpose_cvt<<<dim3(8, 8),  256, 0, stream>>>(Wout + (long)l * 65536,  wT + OUTT + l * 65536, 256, 256);
        transpose_cvt<<<dim3(32, 8), 256, 0, stream>>>(W1 + (long)l * 262144,   wT + W1T + l * 262144, 256, 1024);
        transpose_cvt<<<dim3(8, 32), 256, 0, stream>>>(W2 + (long)l * 262144,   wT + W2T + l * 262144, 1024, 256);
    }

    // pw -> bf16 (already N x K layout)
    const int LC[4] = {2048, 1024, 512, 256};
    long pwoff[4];
    {
        long o = 0;
        for (int lv = 0; lv < 4; ++lv) { pwoff[lv] = o; o += (long)LC[lv] * 256; }
    }
    for (int lv = 0; lv < 4; ++lv)
        cvt_bf<<<(int)((LC[lv] * 256 + 255) / 256), 256, 0, stream>>>(
            pw[lv], pwbf + pwoff[lv], (long)LC[lv] * 256);

    const int LHW[4]   = {256, 1024, 4096, 16384};
    const int LSH[4]   = {8, 10, 12, 14};
    const int LBASE[4] = {0, 256, 1280, 5376};
    for (int lv = 0; lv < 4; ++lv) {
        const int HW = LHW[lv], C = LC[lv];
        // xT (B*HW, C) bf16 in d_out scratch
        transpose_cvt_x<<<dim3(HW / 32, C / 32, NB), 256, 0, stream>>>(
            x[lv], (unsigned short*)Bbuf, C, HW);
        // z (B*HW, 256) fp32 = xT @ pw^T + pb
        gemm_bf<128><<<dim3(2, NB * HW / 128), 256, 0, stream>>>(
            (const unsigned short*)Bbuf, pwbf + pwoff[lv], C,
            zbuf, nullptr, 256, pb[lv], 0);
        gn_stats2<<<dim3(HW / 64, NB), 256, 0, stream>>>(zbuf, stats + lv * 128, HW, 64);
        const long total4 = (long)NB * HW * 64;
        gn_scale<<<(int)((total4 + 255) / 256), 256, 0, stream>>>(
            zbuf, src, src_bf, stats + lv * 128, gg[lv], gb[lv],
            LSH[lv], LBASE[lv], total4);
    }

    for (int l = 0; l < 3; ++l) {
        // q = src + pos -> shbf (bf16)
        make_q2<<<10880, 256, 0, stream>>>(src, posbf, shbf, M * 64);
        // off+attn combined: (M,256)@(256,192) -> oab bf16
        gemm_bf<64><<<dim3(3, 340), 256, 0, stream>>>(
            shbf, wT + OAT + (long)l * 49152, 256, nullptr, oab, 192,
            biasoa + l * 192, 0);
        softmax16_bf<<<680, 256, 0, stream>>>(oab, M * 4);
        // value proj: src_bf @ Wval^T -> Bbuf bf16
        gemm_bf<128><<<dim3(2, 340), 256, 0, stream>>>(
            src_bf, wT + VALT + (long)l * 65536, 256, nullptr, (unsigned short*)Bbuf, 256,
            bval + l * 256, 0);
        // sampling -> shbf bf16 (q dead)
        msda4<<<10880, 256, 0, stream>>>((const unsigned short*)Bbuf, oab, shbf);
        // output proj: shbf @ Wout^T -> Bbuf fp32 (val dead)
        gemm_bf<128><<<dim3(2, 340), 256, 0, stream>>>(
            shbf, wT + OUTT + (long)l * 65536, 256, Bbuf, nullptr, 256,
            bout + l * 256, 0);
        // residual + LN -> shbf bf16 (att dead)
        ln_residual<<<(int)M, 256, 0, stream>>>(src, Bbuf, shbf, ng + l * 256, nbb + l * 256);
        // FFN in halves; hidden bf16 lives in d_out (l<2) or dead src (l==2)
        unsigned short* hid = (l < 2) ? (unsigned short*)d_out : (unsigned short*)src;
        for (int hf = 0; hf < 2; ++hf) {
            const long r0 = (long)hf * (M / 2);
            gemm_bf<128><<<dim3(8, 170), 256, 0, stream>>>(
                shbf + r0 * 256, wT + W1T + (long)l * 262144, 256,
                nullptr, hid, 1024, b1 + l * 1024, 1);
            float* cf = ((l < 2) ? src : (float*)d_out) + r0 * 256;
            unsigned short* cb = (l < 2) ? (src_bf + r0 * 256) : nullptr;
            gemm_bf<128><<<dim3(2, 170), 256, 0, stream>>>(
                hid, wT + W2T + (long)l * 262144, 1024,
                cf, cb, 256, b2 + l * 256, 0);
        }
    }
}

// Round 9
// 1376.497 us; speedup vs baseline: 3.9244x; 1.1798x over previous
//
#include <hip/hip_runtime.h>
#include <math.h>

#define LQ 21760
#define NB 2
// levels: (16,16),(32,32),(64,64),(128,128); bases 0,256,1280,5376

typedef __attribute__((ext_vector_type(8))) short bf16x8;
typedef __attribute__((ext_vector_type(4))) float f32x4;

static __device__ __forceinline__ float wave_sum(float v) {
#pragma unroll
    for (int o = 32; o > 0; o >>= 1) v += __shfl_down(v, o, 64);
    return v;
}

static __device__ __forceinline__ unsigned short f2bf(float f) {
    unsigned int u = __float_as_uint(f);
    u = (u + 0x7fffu + ((u >> 16) & 1u)) >> 16;
    return (unsigned short)u;
}
static __device__ __forceinline__ float bf2f(unsigned short h) {
    return __uint_as_float((unsigned int)h << 16);
}
static __device__ __forceinline__ float bflo(unsigned int u) {
    return __uint_as_float(u << 16);
}
static __device__ __forceinline__ float bfhi(unsigned int u) {
    return __uint_as_float(u & 0xffff0000u);
}

// async global->LDS 16B (linear dest: wave-uniform base + lane*16)
static __device__ __forceinline__ void gload16(const void* g, void* l) {
    __builtin_amdgcn_global_load_lds(
        (const __attribute__((address_space(1))) unsigned int*)g,
        (__attribute__((address_space(3))) unsigned int*)l, 16, 0, 0);
}

__global__ __launch_bounds__(256) void zero_buf(float* __restrict__ p, int n) {
    const int i = blockIdx.x * 256 + threadIdx.x;
    if (i < n) p[i] = 0.f;
}

__global__ __launch_bounds__(256) void bias_cat(const float* __restrict__ boff,
                                                const float* __restrict__ battn,
                                                float* __restrict__ out) {
    const int idx = blockIdx.x * 256 + threadIdx.x;
    if (idx >= 3 * 192) return;
    const int l = idx / 192, i = idx - l * 192;
    out[idx] = (i < 128) ? boff[l * 128 + i] : battn[l * 64 + (i - 128)];
}

__global__ __launch_bounds__(256) void cvt_bf(const float* __restrict__ in,
                                              unsigned short* __restrict__ out, long n) {
    const long i = (long)blockIdx.x * 256 + threadIdx.x;
    if (i < n) out[i] = f2bf(in[i]);
}

// transpose + cvt: in (Kr x Nc) fp32 -> out (Nc x Kr) bf16. grid (Nc/32, Kr/32)
__global__ __launch_bounds__(256) void transpose_cvt(const float* __restrict__ in,
                                                     unsigned short* __restrict__ out,
                                                     int Kr, int Nc)
{
    __shared__ float t[32][33];
    const int n0 = blockIdx.x * 32, k0 = blockIdx.y * 32;
    const int c = threadIdx.x & 31, r8 = threadIdx.x >> 5;
#pragma unroll
    for (int j = 0; j < 4; ++j) {
        const int r = r8 + j * 8;
        t[r][c] = in[(long)(k0 + r) * Nc + n0 + c];
    }
    __syncthreads();
#pragma unroll
    for (int j = 0; j < 4; ++j) {
        const int r = r8 + j * 8;
        out[(long)(n0 + r) * Kr + k0 + c] = f2bf(t[c][r]);
    }
}

// batch transpose+cvt: in (B, C, HW) fp32 -> out (B, HW, C) bf16. grid (HW/32, C/32, B)
__global__ __launch_bounds__(256) void transpose_cvt_x(const float* __restrict__ in,
                                                       unsigned short* __restrict__ out,
                                                       int C, int HW)
{
    __shared__ float t[32][33];
    const int hw0 = blockIdx.x * 32, c0 = blockIdx.y * 32;
    const int b = blockIdx.z;
    in  += (long)b * C * HW;
    out += (long)b * HW * C;
    const int cc = threadIdx.x & 31, rr = threadIdx.x >> 5;
#pragma unroll
    for (int j = 0; j < 4; ++j) {
        const int r = rr + j * 8;
        t[r][cc] = in[(long)(c0 + r) * HW + hw0 + cc];
    }
    __syncthreads();
#pragma unroll
    for (int j = 0; j < 4; ++j) {
        const int r = rr + j * 8;
        out[(long)(hw0 + r) * C + c0 + cc] = f2bf(t[cc][r]);
    }
}

// ---------------- bf16 MFMA GEMM: C(MxN) = A(MxK) @ Bt(NxK)^T ---------------
// A row-major bf16 (lda=K), Bt row-major bf16 (N x K). BM=128, BK=64.
// LDS: linear physical layout (global_load_lds) + XOR swizzle:
//   logical (row, colbyte) stored at physical row*128 + (colbyte ^ ((row&7)<<4))
template<int BN>
__global__ __launch_bounds__(256) void gemm_bf(
    const unsigned short* __restrict__ A, const unsigned short* __restrict__ Bt, int K,
    float* __restrict__ Cf, unsigned short* __restrict__ Cb, int ldc,
    const float* __restrict__ bias, int relu)
{
    constexpr int BM = 128, BK = 64;
    constexpr int BINST = (BN == 128) ? 4 : 2;   // 1KB gload insts per wave for B
    __shared__ unsigned short As[BM * BK];
    __shared__ unsigned short Bs[BN * BK];
    const int tid = threadIdx.x;
    const long m0 = (long)blockIdx.y * BM;
    const int n0 = blockIdx.x * BN;
    const int wave = tid >> 6, lane = tid & 63;
    constexpr int WM = (BN == 128) ? 2 : 4;
    constexpr int FM = (BN == 128) ? 4 : 2;
    const int wm = wave % WM, wn = wave / WM;
    const int wm0 = wm * (BM / WM), wn0 = wn * 64;
    const int lrow = lane & 15, lk8 = (lane >> 4) * 8;
    const int axor = (lrow & 7) << 4;            // read-side swizzle (uniform per lane)
    f32x4 acc[FM][4] = {};
    // staging source coords: physical byte p -> row p>>7, logical colbyte (p&127)^((row&7)<<4)
    int arow[4], acolb[4], brow[BINST], bcolb[BINST];
#pragma unroll
    for (int j = 0; j < 4; ++j) {
        const int p = (wave * 4 + j) * 1024 + lane * 16;
        const int r = p >> 7;
        arow[j] = r;
        acolb[j] = (p & 127) ^ ((r & 7) << 4);
    }
#pragma unroll
    for (int j = 0; j < BINST; ++j) {
        const int p = (wave * BINST + j) * 1024 + lane * 16;
        const int r = p >> 7;
        brow[j] = r;
        bcolb[j] = (p & 127) ^ ((r & 7) << 4);
    }
    for (int k0 = 0; k0 < K; k0 += BK) {
        __syncthreads();
#pragma unroll
        for (int j = 0; j < 4; ++j)
            gload16(A + (m0 + arow[j]) * (long)K + k0 + (acolb[j] >> 1),
                    (char*)As + (wave * 4 + j) * 1024 + lane * 16);
#pragma unroll
        for (int j = 0; j < BINST; ++j)
            gload16(Bt + (long)(n0 + brow[j]) * K + k0 + (bcolb[j] >> 1),
                    (char*)Bs + (wave * BINST + j) * 1024 + lane * 16);
        __syncthreads();
        bf16x8 af[FM][2], bfr[4][2];
#pragma unroll
        for (int i = 0; i < FM; ++i)
#pragma unroll
            for (int kk = 0; kk < 2; ++kk) {
                const int row = wm0 + i * 16 + lrow;
                const int cb = ((kk * 32 + lk8) << 1) ^ axor;
                af[i][kk] = *(const bf16x8*)((const char*)As + (row << 7) + cb);
            }
#pragma unroll
        for (int j = 0; j < 4; ++j)
#pragma unroll
            for (int kk = 0; kk < 2; ++kk) {
                const int row = wn0 + j * 16 + lrow;
                const int cb = ((kk * 32 + lk8) << 1) ^ axor;
                bfr[j][kk] = *(const bf16x8*)((const char*)Bs + (row << 7) + cb);
            }
#pragma unroll
        for (int i = 0; i < FM; ++i)
#pragma unroll
            for (int j = 0; j < 4; ++j)
#pragma unroll
                for (int kk = 0; kk < 2; ++kk)
                    acc[i][j] = __builtin_amdgcn_mfma_f32_16x16x32_bf16(
                        af[i][kk], bfr[j][kk], acc[i][j], 0, 0, 0);
    }
    const int rbase = (lane >> 4) * 4;
#pragma unroll
    for (int i = 0; i < FM; ++i) {
#pragma unroll
        for (int j = 0; j < 4; ++j) {
            const int col = n0 + wn0 + j * 16 + lrow;
            const float bb = bias ? bias[col] : 0.f;
#pragma unroll
            for (int r = 0; r < 4; ++r) {
                float v = acc[i][j][r] + bb;
                if (relu) v = fmaxf(v, 0.f);
                const long row = m0 + wm0 + i * 16 + rbase + r;
                const long idx = row * (long)ldc + col;
                if (Cf) Cf[idx] = v;
                if (Cb) Cb[idx] = f2bf(v);
            }
        }
    }
}

// ---------------- sine pos + level embed -> bf16 table ----------------------
__global__ __launch_bounds__(256) void pos_kernel(unsigned short* __restrict__ pos,
                                                  const float* __restrict__ lvl_emb)
{
    const int idx = blockIdx.x * 256 + threadIdx.x;  // < LQ*256
    const int d = idx & 255;
    const int i = idx >> 8;
    int lv, sz;
    if (i < 256)       { lv = 0; sz = 16; }
    else if (i < 1280) { lv = 1; sz = 32; }
    else if (i < 5376) { lv = 2; sz = 64; }
    else               { lv = 3; sz = 128; }
    const int base = (lv == 0) ? 0 : (lv == 1) ? 256 : (lv == 2) ? 1280 : 5376;
    const int hw = i - base;
    const int hy = hw / sz, wx = hw - hy * sz;
    const int dd = d & 127;
    const float twopi = 6.283185307179586f;
    const float e = ((d < 128) ? (float)(hy + 1) : (float)(wx + 1))
                    / ((float)sz + 1e-6f) * twopi;
    const float t = powf(10000.0f, (float)(2 * (dd >> 1)) * (1.0f / 128.0f));
    const float p = e / t;
    const float v = (dd & 1) ? cosf(p) : sinf(p);
    pos[idx] = f2bf(v + lvl_emb[lv * 256 + d]);
}

// ---------------- q = src + pos (vectorized x4) -> bf16 ---------------------
__global__ __launch_bounds__(256) void make_q2(const float* __restrict__ src,
                                               const unsigned short* __restrict__ pos,
                                               unsigned short* __restrict__ q, long total4)
{
    const long t = (long)blockIdx.x * 256 + threadIdx.x;
    if (t >= total4) return;
    const long idx = t * 4;
    const long pe = (idx >= (long)LQ * 256) ? idx - (long)LQ * 256 : idx;
    const float4 s = *(const float4*)(src + idx);
    const ushort4 pp = *(const ushort4*)(pos + pe);
    unsigned short o[4] = {f2bf(s.x + bf2f(pp.x)), f2bf(s.y + bf2f(pp.y)),
                           f2bf(s.z + bf2f(pp.z)), f2bf(s.w + bf2f(pp.w))};
    *(ushort4*)(q + idx) = *(const ushort4*)o;
}

// ---------------- group-norm stats on (B,HW,256) layout ---------------------
__global__ __launch_bounds__(256) void gn_stats2(const float* __restrict__ z,
                                                 float* __restrict__ stats,
                                                 int HW, int span)
{
    const int b = blockIdx.y;
    const int hw0 = blockIdx.x * span;
    const int d = threadIdx.x;
    float s = 0.f, sq = 0.f;
    const float* p = z + ((long)b * HW + hw0) * 256 + d;
    for (int i = 0; i < span; ++i) {
        const float v = p[(long)i * 256];
        s += v; sq += v * v;
    }
#pragma unroll
    for (int o = 1; o < 8; o <<= 1) {
        s += __shfl_xor(s, o, 64);
        sq += __shfl_xor(sq, o, 64);
    }
    if ((d & 7) == 0) {
        atomicAdd(&stats[(b * 32 + (d >> 3)) * 2 + 0], s);
        atomicAdd(&stats[(b * 32 + (d >> 3)) * 2 + 1], sq);
    }
}

// ---------------- group-norm scale (B,HW,256) -> src fp32 + bf16 ------------
__global__ __launch_bounds__(256) void gn_scale(const float* __restrict__ z,
                                                float* __restrict__ src,
                                                unsigned short* __restrict__ src_bf,
                                                const float* __restrict__ stats,
                                                const float* __restrict__ gg,
                                                const float* __restrict__ gb,
                                                int hwShift, int lvl_base, long total4)
{
    const long t = (long)blockIdx.x * 256 + threadIdx.x;
    if (t >= total4) return;
    const int d4 = (int)(t & 63) * 4;
    const long row = t >> 6;                       // b*HW + hw
    const int b = (int)(row >> hwShift);
    const int hw = (int)(row & ((1 << hwShift) - 1));
    const int g = d4 >> 3;
    const float s = stats[(b * 32 + g) * 2 + 0];
    const float sq = stats[(b * 32 + g) * 2 + 1];
    const float cnt = 8.0f * (float)(1 << hwShift);
    const float m = s / cnt;
    const float rstd = rsqrtf(sq / cnt - m * m + 1e-5f);
    const float4 v = *(const float4*)(z + row * 256 + d4);
    float o[4];
    o[0] = (v.x - m) * rstd * gg[d4 + 0] + gb[d4 + 0];
    o[1] = (v.y - m) * rstd * gg[d4 + 1] + gb[d4 + 1];
    o[2] = (v.z - m) * rstd * gg[d4 + 2] + gb[d4 + 2];
    o[3] = (v.w - m) * rstd * gg[d4 + 3] + gb[d4 + 3];
    const long oidx = ((long)b * LQ + lvl_base + hw) * 256 + d4;
    *(float4*)(src + oidx) = make_float4(o[0], o[1], o[2], o[3]);
    unsigned short ob[4] = {f2bf(o[0]), f2bf(o[1]), f2bf(o[2]), f2bf(o[3])};
    *(ushort4*)(src_bf + oidx) = *(const ushort4*)ob;
}

// ---------------- softmax over 16 bf16 at oa[row*192 + 128 + part*16] -------
__global__ __launch_bounds__(256) void softmax16_bf(unsigned short* __restrict__ oa, long total)
{
    const long t = (long)blockIdx.x * 256 + threadIdx.x;
    if (t >= total) return;
    unsigned short* p = oa + (t >> 2) * 192 + 128 + (t & 3) * 16;
    float v[16];
    float mx = -1e30f;
#pragma unroll
    for (int i = 0; i < 16; ++i) { v[i] = bf2f(p[i]); mx = fmaxf(mx, v[i]); }
    float s = 0.f;
#pragma unroll
    for (int i = 0; i < 16; ++i) { v[i] = __expf(v[i] - mx); s += v[i]; }
    const float inv = 1.0f / s;
#pragma unroll
    for (int i = 0; i < 16; ++i) p[i] = f2bf(v[i] * inv);
}

// ---------------- MS deformable attention: 2 queries/wave, 8 ch/lane --------
__global__ __launch_bounds__(256) void msda8(const unsigned short* __restrict__ val,
                                             const unsigned short* __restrict__ oa,
                                             unsigned short* __restrict__ out)
{
    const int w = (blockIdx.x * 256 + threadIdx.x) >> 6;   // wave id < NB*LQ/2
    const int lane = threadIdx.x & 63;
    const int bq = w * 2 + (lane >> 5);
    const int h = (lane >> 3) & 3;
    const int c8 = (lane & 7) * 8;
    const int q = bq % LQ;
    const int b = bq / LQ;
    int Hq, bq0;
    if (q < 256)       { Hq = 16;  bq0 = 0; }
    else if (q < 1280) { Hq = 32;  bq0 = 256; }
    else if (q < 5376) { Hq = 64;  bq0 = 1280; }
    else               { Hq = 128; bq0 = 5376; }
    const int hw = q - bq0;
    const int qy = hw / Hq, qx = hw - qy * Hq;
    const float refx = ((float)qx + 0.5f) / (float)Hq;
    const float refy = ((float)qy + 0.5f) / (float)Hq;
    const unsigned short* oar = oa + (long)bq * 192;
    const int LH[4] = {16, 32, 64, 128};
    const int LB[4] = {0, 256, 1280, 5376};
    float a0 = 0.f, a1 = 0.f, a2 = 0.f, a3 = 0.f;
    float a4 = 0.f, a5 = 0.f, a6 = 0.f, a7 = 0.f;
#pragma unroll
    for (int lv = 0; lv < 4; ++lv) {
        const int Hl = LH[lv];
        const unsigned short* vb = val + ((long)b * LQ + LB[lv]) * 256 + h * 64 + c8;
#pragma unroll
        for (int p = 0; p < 4; ++p) {
            const unsigned int oxy = *(const unsigned int*)(oar + h * 32 + (lv * 4 + p) * 2);
            const float ox = bf2f((unsigned short)(oxy & 0xffffu));
            const float oy = bf2f((unsigned short)(oxy >> 16));
            const float wgt = bf2f(oar[128 + h * 16 + lv * 4 + p]);
            const float x = refx * (float)Hl + ox - 0.5f;
            const float y = refy * (float)Hl + oy - 0.5f;
            const float xf = floorf(x), yf = floorf(y);
            const float tx = x - xf, ty = y - yf;
            const int x0 = (int)xf, y0 = (int)yf;
            const float w00 = wgt * (1.f - ty) * (1.f - tx), w01 = wgt * (1.f - ty) * tx;
            const float w10 = wgt * ty * (1.f - tx),         w11 = wgt * ty * tx;
            const bool xv0 = (x0 >= 0) & (x0 < Hl);
            const bool xv1 = (x0 + 1 >= 0) & (x0 + 1 < Hl);
#define SAMPLE(WT, IDX) { const uint4 vv = *(const uint4*)(vb + (long)(IDX) * 256); \
        a0 += (WT) * bflo(vv.x); a1 += (WT) * bfhi(vv.x); \
        a2 += (WT) * bflo(vv.y); a3 += (WT) * bfhi(vv.y); \
        a4 += (WT) * bflo(vv.z); a5 += (WT) * bfhi(vv.z); \
        a6 += (WT) * bflo(vv.w); a7 += (WT) * bfhi(vv.w); }
            if (y0 >= 0 && y0 < Hl) {
                const int r = y0 * Hl;
                if (xv0) SAMPLE(w00, r + x0)
                if (xv1) SAMPLE(w01, r + x0 + 1)
            }
            if (y0 + 1 >= 0 && y0 + 1 < Hl) {
                const int r = (y0 + 1) * Hl;
                if (xv0) SAMPLE(w10, r + x0)
                if (xv1) SAMPLE(w11, r + x0 + 1)
            }
#undef SAMPLE
        }
    }
    unsigned int r0 = (unsigned int)f2bf(a0) | ((unsigned int)f2bf(a1) << 16);
    unsigned int r1 = (unsigned int)f2bf(a2) | ((unsigned int)f2bf(a3) << 16);
    unsigned int r2 = (unsigned int)f2bf(a4) | ((unsigned int)f2bf(a5) << 16);
    unsigned int r3 = (unsigned int)f2bf(a6) | ((unsigned int)f2bf(a7) << 16);
    uint4 o = make_uint4(r0, r1, r2, r3);
    *(uint4*)(out + (long)bq * 256 + h * 64 + c8) = o;
}

// ---------------- residual + layer-norm -> bf16 out -------------------------
__global__ __launch_bounds__(256) void ln_residual(const float* __restrict__ src,
                                                   const float* __restrict__ att,
                                                   unsigned short* __restrict__ outb,
                                                   const float* __restrict__ g,
                                                   const float* __restrict__ b)
{
    const long row = blockIdx.x;
    const int d = threadIdx.x;
    const long idx = row * 256 + d;
    const float v = src[idx] + att[idx];
    float s = wave_sum(v), sq = wave_sum(v * v);
    __shared__ float sh[8];
    const int wid = d >> 6, lane = d & 63;
    if (lane == 0) { sh[wid] = s; sh[4 + wid] = sq; }
    __syncthreads();
    const float S = sh[0] + sh[1] + sh[2] + sh[3];
    const float SQ = sh[4] + sh[5] + sh[6] + sh[7];
    const float m = S * (1.0f / 256.0f);
    const float var = SQ * (1.0f / 256.0f) - m * m;
    const float r = rsqrtf(var + 1e-5f);
    outb[idx] = f2bf((v - m) * r * g[d] + b[d]);
}

extern "C" void kernel_launch(void* const* d_in, const int* in_sizes, int n_in,
                              void* d_out, int out_size, void* d_ws, size_t ws_size,
                              hipStream_t stream)
{
    const float* x[4]  = {(const float*)d_in[0],  (const float*)d_in[5],
                          (const float*)d_in[10], (const float*)d_in[15]};
    const float* pw[4] = {(const float*)d_in[1],  (const float*)d_in[6],
                          (const float*)d_in[11], (const float*)d_in[16]};
    const float* pb[4] = {(const float*)d_in[2],  (const float*)d_in[7],
                          (const float*)d_in[12], (const float*)d_in[17]};
    const float* gg[4] = {(const float*)d_in[3],  (const float*)d_in[8],
                          (const float*)d_in[13], (const float*)d_in[18]};
    const float* gb[4] = {(const float*)d_in[4],  (const float*)d_in[9],
                          (const float*)d_in[14], (const float*)d_in[19]};
    const float* lvl_emb = (const float*)d_in[20];
    const float* Woff  = (const float*)d_in[21];
    const float* boff  = (const float*)d_in[22];
    const float* Wattn = (const float*)d_in[23];
    const float* battn = (const float*)d_in[24];
    const float* Wval  = (const float*)d_in[25];
    const float* bval  = (const float*)d_in[26];
    const float* Wout  = (const float*)d_in[27];
    const float* bout  = (const float*)d_in[28];
    const float* ng    = (const float*)d_in[29];
    const float* nbb   = (const float*)d_in[30];
    const float* W1    = (const float*)d_in[31];
    const float* b1    = (const float*)d_in[32];
    const float* W2    = (const float*)d_in[33];
    const float* b2    = (const float*)d_in[34];

    // ---- workspace layout (float offsets)
    const long M = (long)NB * LQ;                 // 43520
    const long SRC_F    = 0;                      // fp32 src        11,141,120 f
    const long SRCBF_F  = 11141120;               // bf16 src         5,570,560 f
    const long SHARED_F = SRCBF_F + 5570560;      // bf16 q/att/ln    5,570,560 f
    const long OA_F     = SHARED_F + 5570560;     // bf16 M*192       4,177,920 f
    const long POS_F    = OA_F + 4177920;         // bf16 LQ*256      2,785,280 f
    const long WT_F     = POS_F + 2785280;        // bf16 weights     1,056,768 f
    const long BIAS_F   = WT_F + 1056768;         // 576 f
    const long STATS_F  = BIAS_F + 576;           // 512 f
    const long NEED_F   = STATS_F + 512;          // 30,303,296 f = 121.2 MB
    if (ws_size < (size_t)NEED_F * sizeof(float)) return;

    float* ws = (float*)d_ws;
    float*          src    = ws + SRC_F;
    unsigned short* src_bf = (unsigned short*)(ws + SRCBF_F);
    unsigned short* shbf   = (unsigned short*)(ws + SHARED_F);
    unsigned short* oab    = (unsigned short*)(ws + OA_F);
    unsigned short* posbf  = (unsigned short*)(ws + POS_F);
    unsigned short* wT     = (unsigned short*)(ws + WT_F);
    float*          biasoa = ws + BIAS_F;
    float*          stats  = ws + STATS_F;
    // conv-phase overlays: zbuf needs max 2*16384*256 = 8,388,608 f in SHARED+OA;
    // pw_bf (983,040 ushorts = 491,520 f) lives in the tail of OA after zbuf.
    float*          zbuf   = ws + SHARED_F;
    unsigned short* pwbf   = (unsigned short*)(ws + SHARED_F + 8388608);
    float*          Bbuf   = (float*)d_out;       // xT / val / attn-proj scratch

    // bf16 transposed weight offsets (ushort units)
    const long OAT = 0;                 // 3 * 192*256
    const long VALT = OAT + 3 * 49152;  // 3 * 65536
    const long OUTT = VALT + 3 * 65536;
    const long W1T = OUTT + 3 * 65536;  // 3 * 1024*256
    const long W2T = W1T + 3 * 262144;  // 3 * 256*1024

    zero_buf<<<2, 256, 0, stream>>>(stats, 512);
    bias_cat<<<3, 256, 0, stream>>>(boff, battn, biasoa);
    pos_kernel<<<LQ, 256, 0, stream>>>(posbf, lvl_emb);
    for (int l = 0; l < 3; ++l) {
        transpose_cvt<<<dim3(4, 8),  256, 0, stream>>>(Woff + (long)l * 32768,  wT + OAT + l * 49152, 256, 128);
        transpose_cvt<<<dim3(2, 8),  256, 0, stream>>>(Wattn + (long)l * 16384, wT + OAT + l * 49152 + 128 * 256, 256, 64);
        transpose_cvt<<<dim3(8, 8),  256, 0, stream>>>(Wval + (long)l * 65536,  wT + VALT + l * 65536, 256, 256);
        transpose_cvt<<<dim3(8, 8),  256, 0, stream>>>(Wout + (long)l * 65536,  wT + OUTT + l * 65536, 256, 256);
        transpose_cvt<<<dim3(32, 8), 256, 0, stream>>>(W1 + (long)l * 262144,   wT + W1T + l * 262144, 256, 1024);
        transpose_cvt<<<dim3(8, 32), 256, 0, stream>>>(W2 + (long)l * 262144,   wT + W2T + l * 262144, 1024, 256);
    }

    // pw -> bf16 (already N x K layout)
    const int LC[4] = {2048, 1024, 512, 256};
    long pwoff[4];
    {
        long o = 0;
        for (int lv = 0; lv < 4; ++lv) { pwoff[lv] = o; o += (long)LC[lv] * 256; }
    }
    for (int lv = 0; lv < 4; ++lv)
        cvt_bf<<<(int)((LC[lv] * 256 + 255) / 256), 256, 0, stream>>>(
            pw[lv], pwbf + pwoff[lv], (long)LC[lv] * 256);

    const int LHW[4]   = {256, 1024, 4096, 16384};
    const int LSH[4]   = {8, 10, 12, 14};
    const int LBASE[4] = {0, 256, 1280, 5376};
    for (int lv = 0; lv < 4; ++lv) {
        const int HW = LHW[lv], C = LC[lv];
        // xT (B*HW, C) bf16 in d_out scratch
        transpose_cvt_x<<<dim3(HW / 32, C / 32, NB), 256, 0, stream>>>(
            x[lv], (unsigned short*)Bbuf, C, HW);
        // z (B*HW, 256) fp32 = xT @ pw^T + pb
        gemm_bf<128><<<dim3(2, NB * HW / 128), 256, 0, stream>>>(
            (const unsigned short*)Bbuf, pwbf + pwoff[lv], C,
            zbuf, nullptr, 256, pb[lv], 0);
        gn_stats2<<<dim3(HW / 64, NB), 256, 0, stream>>>(zbuf, stats + lv * 128, HW, 64);
        const long total4 = (long)NB * HW * 64;
        gn_scale<<<(int)((total4 + 255) / 256), 256, 0, stream>>>(
            zbuf, src, src_bf, stats + lv * 128, gg[lv], gb[lv],
            LSH[lv], LBASE[lv], total4);
    }

    for (int l = 0; l < 3; ++l) {
        // q = src + pos -> shbf (bf16)
        make_q2<<<10880, 256, 0, stream>>>(src, posbf, shbf, M * 64);
        // off+attn combined: (M,256)@(256,192) -> oab bf16
        gemm_bf<64><<<dim3(3, 340), 256, 0, stream>>>(
            shbf, wT + OAT + (long)l * 49152, 256, nullptr, oab, 192,
            biasoa + l * 192, 0);
        softmax16_bf<<<680, 256, 0, stream>>>(oab, M * 4);
        // value proj: src_bf @ Wval^T -> Bbuf bf16
        gemm_bf<128><<<dim3(2, 340), 256, 0, stream>>>(
            src_bf, wT + VALT + (long)l * 65536, 256, nullptr, (unsigned short*)Bbuf, 256,
            bval + l * 256, 0);
        // sampling -> shbf bf16 (q dead); 2 queries per wave
        msda8<<<5440, 256, 0, stream>>>((const unsigned short*)Bbuf, oab, shbf);
        // output proj: shbf @ Wout^T -> Bbuf fp32 (val dead)
        gemm_bf<128><<<dim3(2, 340), 256, 0, stream>>>(
            shbf, wT + OUTT + (long)l * 65536, 256, Bbuf, nullptr, 256,
            bout + l * 256, 0);
        // residual + LN -> shbf bf16 (att dead)
        ln_residual<<<(int)M, 256, 0, stream>>>(src, Bbuf, shbf, ng + l * 256, nbb + l * 256);
        // FFN in halves; hidden bf16 lives in d_out (l<2) or dead src (l==2)
        unsigned short* hid = (l < 2) ? (unsigned short*)d_out : (unsigned short*)src;
        for (int hf = 0; hf < 2; ++hf) {
            const long r0 = (long)hf * (M / 2);
            gemm_bf<128><<<dim3(8, 170), 256, 0, stream>>>(
                shbf + r0 * 256, wT + W1T + (long)l * 262144, 256,
                nullptr, hid, 1024, b1 + l * 1024, 1);
            float* cf = ((l < 2) ? src : (float*)d_out) + r0 * 256;
            unsigned short* cb = (l < 2) ? (src_bf + r0 * 256) : nullptr;
            gemm_bf<128><<<dim3(2, 170), 256, 0, stream>>>(
                hid, wT + W2T + (long)l * 262144, 1024,
                cf, cb, 256, b2 + l * 256, 0);
        }
    }
}